// Round 1
// baseline (763.117 us; speedup 1.0000x reference)
//
#include <hip/hip_runtime.h>
#include <math.h>

#define N_NODES 50000
#define N_EDGES 800000
#define F_IN    128
#define HC      64
#define NG      128
#define NCLS    10

// ---------------- CSR build (dst-sorted) ----------------
__global__ void hist_kernel(const int* __restrict__ dst, int* __restrict__ counts, int e) {
    int t = blockIdx.x * blockDim.x + threadIdx.x;
    if (t < e) atomicAdd(&counts[dst[t]], 1);
}

__global__ void scan_kernel(const int* __restrict__ counts, int* __restrict__ row_ptr,
                            int* __restrict__ fillp, int n) {
    __shared__ int tmp[1024];
    __shared__ int carry;
    int tid = threadIdx.x;
    if (tid == 0) carry = 0;
    __syncthreads();
    for (int base = 0; base < n; base += 1024) {
        int i = base + tid;
        int v = (i < n) ? counts[i] : 0;
        tmp[tid] = v;
        __syncthreads();
        for (int off = 1; off < 1024; off <<= 1) {
            int t = (tid >= off) ? tmp[tid - off] : 0;
            __syncthreads();
            tmp[tid] += t;
            __syncthreads();
        }
        int excl = carry + tmp[tid] - v;
        if (i < n) { row_ptr[i] = excl; fillp[i] = excl; }
        __syncthreads();
        if (tid == 0) carry += tmp[1023];
        __syncthreads();
    }
    if (tid == 0) row_ptr[n] = carry;
}

__global__ void scatter_kernel(const int* __restrict__ src, const int* __restrict__ dst,
                               int* __restrict__ fillp, int* __restrict__ col_src, int e) {
    int t = blockIdx.x * blockDim.x + threadIdx.x;
    if (t < e) {
        int pos = atomicAdd(&fillp[dst[t]], 1);
        col_src[pos] = src[t];
    }
}

// ---------------- fused 4-way GEMM: out[n][y*64+c] = x@W_y + b_y ----------------
__global__ __launch_bounds__(256) void gemm64_kernel(
    const float* __restrict__ x, int M, int K,
    const float* __restrict__ Wq, const float* __restrict__ Wk,
    const float* __restrict__ Wv, const float* __restrict__ Wsk,
    const float* __restrict__ bq, const float* __restrict__ bk,
    const float* __restrict__ bv, const float* __restrict__ bsk,
    float* __restrict__ out)
{
    __shared__ float sW[F_IN * 64];   // 32 KB max (K<=128)
    const float* W; const float* b;
    switch (blockIdx.y) {
        case 0:  W = Wq;  b = bq;  break;
        case 1:  W = Wk;  b = bk;  break;
        case 2:  W = Wv;  b = bv;  break;
        default: W = Wsk; b = bsk; break;
    }
    int n4 = (K * 64) >> 2;
    const float4* W4 = (const float4*)W;
    for (int t = threadIdx.x; t < n4; t += 256)
        ((float4*)sW)[t] = W4[t];
    __syncthreads();

    int j  = threadIdx.x & 15;       // 16 col groups of 4
    int i  = threadIdx.x >> 4;       // 16 row groups of 4
    int r0 = blockIdx.x * 64 + i * 4;
    float acc[4][4] = {{0.f}};
    for (int k = 0; k < K; k += 4) {
        float xr[4][4];
        #pragma unroll
        for (int rr = 0; rr < 4; ++rr) {
            int r = r0 + rr;
            if (r < M) {
                float4 xv = *(const float4*)(x + (size_t)r * K + k);
                xr[rr][0] = xv.x; xr[rr][1] = xv.y; xr[rr][2] = xv.z; xr[rr][3] = xv.w;
            } else {
                xr[rr][0] = xr[rr][1] = xr[rr][2] = xr[rr][3] = 0.f;
            }
        }
        #pragma unroll
        for (int kk = 0; kk < 4; ++kk) {
            float4 wv = *(const float4*)(sW + (k + kk) * 64 + j * 4);
            #pragma unroll
            for (int rr = 0; rr < 4; ++rr) {
                acc[rr][0] += xr[rr][kk] * wv.x;
                acc[rr][1] += xr[rr][kk] * wv.y;
                acc[rr][2] += xr[rr][kk] * wv.z;
                acc[rr][3] += xr[rr][kk] * wv.w;
            }
        }
    }
    float4 bv4 = *(const float4*)(b + j * 4);
    int ocol = blockIdx.y * 64 + j * 4;
    #pragma unroll
    for (int rr = 0; rr < 4; ++rr) {
        int r = r0 + rr;
        if (r < M) {
            float4 o;
            o.x = acc[rr][0] + bv4.x;
            o.y = acc[rr][1] + bv4.y;
            o.z = acc[rr][2] + bv4.z;
            o.w = acc[rr][3] + bv4.w;
            *(float4*)(out + (size_t)r * 256 + ocol) = o;
        }
    }
}

// ---------------- attention: one wave per dst node, online softmax ----------------
__global__ __launch_bounds__(256) void attn_kernel(
    const float* __restrict__ qkvs,   // [N][256]: q|k|v|skip
    const int* __restrict__ row_ptr,
    const int* __restrict__ col_src,
    float* __restrict__ hout,         // [N][64]
    int n, int do_relu)
{
    int wave = (int)((blockIdx.x * (size_t)blockDim.x + threadIdx.x) >> 6);
    int lane = threadIdx.x & 63;
    if (wave >= n) return;
    const float* qrow = qkvs + (size_t)wave * 256;
    float q = qrow[lane];                 // lane -> (h = lane>>4, c = lane&15)
    float m = -INFINITY, denom = 0.f, acc = 0.f;
    int e0 = row_ptr[wave], e1 = row_ptr[wave + 1];
    for (int e = e0; e < e1; ++e) {
        int s = col_src[e];
        const float* srow = qkvs + (size_t)s * 256;
        float kv = srow[64 + lane];
        float vv = srow[128 + lane];
        float prod = q * kv;
        prod += __shfl_xor(prod, 1, 64);
        prod += __shfl_xor(prod, 2, 64);
        prod += __shfl_xor(prod, 4, 64);
        prod += __shfl_xor(prod, 8, 64);
        float sc = prod * 0.25f;          // / sqrt(C=16)
        float mn = fmaxf(m, sc);
        float scale = __expf(m - mn);
        float p = __expf(sc - mn);
        denom = denom * scale + p;
        acc = acc * scale + p * vv;
        m = mn;
    }
    float outv = acc / (denom + 1e-16f) + qrow[192 + lane];
    if (do_relu) outv = fmaxf(outv, 0.f);
    hout[(size_t)wave * 64 + lane] = outv;
}

// ---------------- pooling + head ----------------
__global__ void graph_ranges_kernel(const int* __restrict__ bm, int* __restrict__ gstart,
                                    int n, int g) {
    int t = blockIdx.x * blockDim.x + threadIdx.x;
    if (t > g) return;
    if (t == g) { gstart[g] = n; return; }
    int lo = 0, hi = n;
    while (lo < hi) { int mid = (lo + hi) >> 1; if (bm[mid] < t) lo = mid + 1; else hi = mid; }
    gstart[t] = lo;
}

__global__ __launch_bounds__(256) void pool_kernel(
    const float* __restrict__ h, const int* __restrict__ gstart,
    float* __restrict__ pooled)
{
    int g = blockIdx.x;
    int c = threadIdx.x & 63, sub = threadIdx.x >> 6;
    int s = gstart[g], e = gstart[g + 1];
    float sum = 0.f;
    for (int i = s + sub; i < e; i += 4) sum += h[(size_t)i * 64 + c];
    __shared__ float tmp[256];
    tmp[threadIdx.x] = sum;
    __syncthreads();
    if (sub == 0) {
        sum = tmp[c] + tmp[c + 64] + tmp[c + 128] + tmp[c + 192];
        int cnt = e - s;
        pooled[g * 64 + c] = sum / fmaxf((float)cnt, 1.0f);
    }
}

__global__ void head_kernel(const float* __restrict__ pooled,
                            const float* __restrict__ Wl, const float* __restrict__ bl,
                            float* __restrict__ out)
{
    int g = blockIdx.x;
    int lane = threadIdx.x;   // 64 threads
    __shared__ float pl[64];
    pl[lane] = pooled[g * 64 + lane];
    __syncthreads();
    float logit = -INFINITY;
    if (lane < NCLS) {
        float acc = bl[lane];
        for (int k = 0; k < 64; ++k) acc += pl[k] * Wl[k * NCLS + lane];
        logit = acc;
    }
    float mx = logit;
    mx = fmaxf(mx, __shfl_xor(mx, 1, 64));
    mx = fmaxf(mx, __shfl_xor(mx, 2, 64));
    mx = fmaxf(mx, __shfl_xor(mx, 4, 64));
    mx = fmaxf(mx, __shfl_xor(mx, 8, 64));
    float ex = (lane < NCLS) ? __expf(logit - mx) : 0.f;
    float sm = ex;
    sm += __shfl_xor(sm, 1, 64);
    sm += __shfl_xor(sm, 2, 64);
    sm += __shfl_xor(sm, 4, 64);
    sm += __shfl_xor(sm, 8, 64);
    if (lane < NCLS) out[g * NCLS + lane] = ex / sm;
}

// ---------------- launch ----------------
extern "C" void kernel_launch(void* const* d_in, const int* in_sizes, int n_in,
                              void* d_out, int out_size, void* d_ws, size_t ws_size,
                              hipStream_t stream) {
    const float* x  = (const float*)d_in[0];
    const int*   ei = (const int*)d_in[1];
    const int*   bm = (const int*)d_in[2];
    const float* W1[4] = {(const float*)d_in[3], (const float*)d_in[5], (const float*)d_in[7], (const float*)d_in[9]};
    const float* B1[4] = {(const float*)d_in[4], (const float*)d_in[6], (const float*)d_in[8], (const float*)d_in[10]};
    const float* W2[4] = {(const float*)d_in[11], (const float*)d_in[13], (const float*)d_in[15], (const float*)d_in[17]};
    const float* B2[4] = {(const float*)d_in[12], (const float*)d_in[14], (const float*)d_in[16], (const float*)d_in[18]};
    const float* W3[4] = {(const float*)d_in[19], (const float*)d_in[21], (const float*)d_in[23], (const float*)d_in[25]};
    const float* B3[4] = {(const float*)d_in[20], (const float*)d_in[22], (const float*)d_in[24], (const float*)d_in[26]};
    const float* Wl = (const float*)d_in[27];
    const float* bl = (const float*)d_in[28];
    float* outp = (float*)d_out;

    // workspace layout
    float* qkvs   = (float*)d_ws;                          // N*256 f32
    float* h      = qkvs + (size_t)N_NODES * 256;          // N*64 f32
    int* row_ptr  = (int*)(h + (size_t)N_NODES * 64);      // N+1
    int* fillp    = row_ptr + (N_NODES + 1);               // N
    int* counts   = fillp + N_NODES;                       // N
    int* col_src  = counts + N_NODES;                      // E
    int* gstart   = col_src + N_EDGES;                     // G+1
    float* pooled = (float*)(gstart + (NG + 1));           // G*64

    const int* srcp = ei;
    const int* dstp = ei + N_EDGES;

    // CSR build (once per call; shared by all 3 layers)
    hipMemsetAsync(counts, 0, N_NODES * sizeof(int), stream);
    hist_kernel<<<(N_EDGES + 255) / 256, 256, 0, stream>>>(dstp, counts, N_EDGES);
    scan_kernel<<<1, 1024, 0, stream>>>(counts, row_ptr, fillp, N_NODES);
    scatter_kernel<<<(N_EDGES + 255) / 256, 256, 0, stream>>>(srcp, dstp, fillp, col_src, N_EDGES);

    dim3 ggrid((N_NODES + 63) / 64, 4);
    int agrid = (N_NODES + 3) / 4;

    // layer 1
    gemm64_kernel<<<ggrid, 256, 0, stream>>>(x, N_NODES, F_IN,
        W1[0], W1[1], W1[2], W1[3], B1[0], B1[1], B1[2], B1[3], qkvs);
    attn_kernel<<<agrid, 256, 0, stream>>>(qkvs, row_ptr, col_src, h, N_NODES, 1);
    // layer 2
    gemm64_kernel<<<ggrid, 256, 0, stream>>>(h, N_NODES, HC,
        W2[0], W2[1], W2[2], W2[3], B2[0], B2[1], B2[2], B2[3], qkvs);
    attn_kernel<<<agrid, 256, 0, stream>>>(qkvs, row_ptr, col_src, h, N_NODES, 1);
    // layer 3 (no relu)
    gemm64_kernel<<<ggrid, 256, 0, stream>>>(h, N_NODES, HC,
        W3[0], W3[1], W3[2], W3[3], B3[0], B3[1], B3[2], B3[3], qkvs);
    attn_kernel<<<agrid, 256, 0, stream>>>(qkvs, row_ptr, col_src, h, N_NODES, 0);

    // pooling + head
    graph_ranges_kernel<<<1, 256, 0, stream>>>(bm, gstart, N_NODES, NG);
    pool_kernel<<<NG, 256, 0, stream>>>(h, gstart, pooled);
    head_kernel<<<NG, 64, 0, stream>>>(pooled, Wl, bl, outp);
}

// Round 2
// 458.160 us; speedup vs baseline: 1.6656x; 1.6656x over previous
//
#include <hip/hip_runtime.h>
#include <math.h>

#define N_NODES 50000
#define NPAD    50048
#define N_EDGES 800000
#define F_IN    128
#define HC      64
#define NG      128
#define NCLS    10

typedef __attribute__((ext_vector_type(8))) short bfrag;   // 8 bf16 (4 VGPR)
typedef __attribute__((ext_vector_type(4))) float f32x4;

__device__ __forceinline__ unsigned short f2bf_rne(float f) {
    unsigned u = __float_as_uint(f);
    unsigned r = u + 0x7FFF + ((u >> 16) & 1);
    return (unsigned short)(r >> 16);
}
__device__ __forceinline__ float bf2f(unsigned short h) {
    return __uint_as_float(((unsigned)h) << 16);
}

// ---------------- CSR build ----------------
__global__ void hist_kernel(const int* __restrict__ dst, int* __restrict__ counts, int e) {
    int t = blockIdx.x * blockDim.x + threadIdx.x;
    if (t < e) atomicAdd(&counts[dst[t]], 1);
}

__global__ __launch_bounds__(1024) void scan_kernel(const int* __restrict__ counts,
                                                    int* __restrict__ row_ptr,
                                                    int* __restrict__ fillp, int n) {
    __shared__ int wsum[16];
    __shared__ int carry_s;
    int tid = threadIdx.x, lane = tid & 63, wid = tid >> 6;
    if (tid == 0) carry_s = 0;
    __syncthreads();
    for (int base = 0; base < n; base += 1024) {
        int i = base + tid;
        int v = (i < n) ? counts[i] : 0;
        int sc = v;
        #pragma unroll
        for (int off = 1; off < 64; off <<= 1) {
            int t = __shfl_up(sc, off, 64);
            if (lane >= off) sc += t;
        }
        if (lane == 63) wsum[wid] = sc;
        __syncthreads();
        if (tid < 16) {
            int s = wsum[tid];
            #pragma unroll
            for (int off = 1; off < 16; off <<= 1) {
                int t = __shfl_up(s, off, 16);
                if (tid >= off) s += t;
            }
            wsum[tid] = s;
        }
        __syncthreads();
        int excl = carry_s + (wid ? wsum[wid - 1] : 0) + (sc - v);
        if (i < n) { row_ptr[i] = excl; fillp[i] = excl; }
        __syncthreads();
        if (tid == 0) carry_s += wsum[15];
        __syncthreads();
    }
    if (threadIdx.x == 0) row_ptr[n] = carry_s;
}

__global__ void scatter_kernel(const int* __restrict__ src, const int* __restrict__ dst,
                               int* __restrict__ fillp, int* __restrict__ col_src, int e) {
    int t = blockIdx.x * blockDim.x + threadIdx.x;
    if (t < e) {
        int pos = atomicAdd(&fillp[dst[t]], 1);
        col_src[pos] = src[t];
    }
}

// ---------------- fp32 -> bf16 hi/lo split (x input) ----------------
__global__ void split_kernel(const float* __restrict__ in, unsigned short* __restrict__ hi,
                             unsigned short* __restrict__ lo, int n4) {
    int t = blockIdx.x * blockDim.x + threadIdx.x;
    if (t >= n4) return;
    float4 f = ((const float4*)in)[t];
    unsigned short h[4], l[4];
    float ff[4] = {f.x, f.y, f.z, f.w};
    #pragma unroll
    for (int i = 0; i < 4; ++i) {
        h[i] = f2bf_rne(ff[i]);
        l[i] = f2bf_rne(ff[i] - bf2f(h[i]));
    }
    ((ushort4*)hi)[t] = make_ushort4(h[0], h[1], h[2], h[3]);
    ((ushort4*)lo)[t] = make_ushort4(l[0], l[1], l[2], l[3]);
}

// ---------------- W [K][64] fp32 -> transposed bf16 hi/lo [mat][64][K] ----------------
__global__ void wconv_kernel(const float* __restrict__ W0, const float* __restrict__ W1,
                             const float* __restrict__ W2, const float* __restrict__ W3,
                             int K, unsigned short* __restrict__ wt_hi,
                             unsigned short* __restrict__ wt_lo) {
    int t = blockIdx.x * blockDim.x + threadIdx.x;
    int per = K * 64;
    if (t >= 4 * per) return;
    int mat = t / per, r = t - mat * per;
    int k = r >> 6, c = r & 63;
    const float* W = (mat == 0) ? W0 : (mat == 1) ? W1 : (mat == 2) ? W2 : W3;
    float f = W[k * 64 + c];
    unsigned short h = f2bf_rne(f);
    unsigned short l = f2bf_rne(f - bf2f(h));
    int idx = mat * per + c * K + k;
    wt_hi[idx] = h;
    wt_lo[idx] = l;
}

// ---------------- split-bf16 MFMA GEMM: out[n][y*64+c] = A @ W_y + b_y ----------------
// A given as hi/lo bf16 [NPAD][K]; Wt as [4][64][K] bf16 hi/lo (transposed).
__global__ __launch_bounds__(256) void mfma_gemm_kernel(
    const unsigned short* __restrict__ A_hi, const unsigned short* __restrict__ A_lo,
    const unsigned short* __restrict__ Wt_hi, const unsigned short* __restrict__ Wt_lo,
    const float* __restrict__ b0, const float* __restrict__ b1,
    const float* __restrict__ b2, const float* __restrict__ b3,
    float* __restrict__ out, int M, int K)
{
    extern __shared__ char smem[];
    const int tileU = 64 * K;                       // ushorts per tile
    unsigned short* sA_hi = (unsigned short*)smem;
    unsigned short* sA_lo = sA_hi + tileU;
    unsigned short* sB_hi = sA_lo + tileU;
    unsigned short* sB_lo = sB_hi + tileU;

    int tid = threadIdx.x;
    int row0 = blockIdx.x * 64;
    int y = blockIdx.y;

    // stage 4 tiles, XOR-swizzled (bits 4-6 of byte offset by row&7)
    int cpr = K >> 3;                               // 16B chunks per row
    int total = 64 * cpr;
    const bfrag* gAh = (const bfrag*)(A_hi + (size_t)row0 * K);
    const bfrag* gAl = (const bfrag*)(A_lo + (size_t)row0 * K);
    const bfrag* gBh = (const bfrag*)(Wt_hi + (size_t)y * tileU);
    const bfrag* gBl = (const bfrag*)(Wt_lo + (size_t)y * tileU);
    for (int t = tid; t < total; t += 256) {
        int row = t / cpr, cs = t - row * cpr;
        int dstB = row * (K * 2) + ((cs * 16) ^ ((row & 7) << 4));
        *(bfrag*)((char*)sA_hi + dstB) = gAh[t];
        *(bfrag*)((char*)sA_lo + dstB) = gAl[t];
        *(bfrag*)((char*)sB_hi + dstB) = gBh[t];
        *(bfrag*)((char*)sB_lo + dstB) = gBl[t];
    }
    __syncthreads();

    int w = tid >> 6, lane = tid & 63, lr = lane & 15, kq = lane >> 4;
    f32x4 acc[4];
    #pragma unroll
    for (int f = 0; f < 4; ++f) acc[f] = (f32x4){0.f, 0.f, 0.f, 0.f};

    int arow = w * 16 + lr;
    int abase = arow * (K * 2);
    int aswz = (arow & 7) << 4;
    for (int ks = 0; ks < K; ks += 32) {
        int kb = ks * 2 + kq * 16;
        bfrag ah = *(const bfrag*)((const char*)sA_hi + abase + (kb ^ aswz));
        bfrag al = *(const bfrag*)((const char*)sA_lo + abase + (kb ^ aswz));
        #pragma unroll
        for (int f = 0; f < 4; ++f) {
            int brow = f * 16 + lr;
            int boff = brow * (K * 2) + (kb ^ ((brow & 7) << 4));
            bfrag bh = *(const bfrag*)((const char*)sB_hi + boff);
            bfrag bl = *(const bfrag*)((const char*)sB_lo + boff);
            acc[f] = __builtin_amdgcn_mfma_f32_16x16x32_bf16(ah, bh, acc[f], 0, 0, 0);
            acc[f] = __builtin_amdgcn_mfma_f32_16x16x32_bf16(ah, bl, acc[f], 0, 0, 0);
            acc[f] = __builtin_amdgcn_mfma_f32_16x16x32_bf16(al, bh, acc[f], 0, 0, 0);
        }
    }

    const float* bias = (y == 0) ? b0 : (y == 1) ? b1 : (y == 2) ? b2 : b3;
    int colbase = y * 64;
    #pragma unroll
    for (int f = 0; f < 4; ++f) {
        float bv = bias[f * 16 + lr];
        #pragma unroll
        for (int r = 0; r < 4; ++r) {
            int gr = row0 + w * 16 + kq * 4 + r;
            if (gr < M) out[(size_t)gr * 256 + colbase + f * 16 + lr] = acc[f][r] + bv;
        }
    }
}

// ---------------- attention: wave per dst node, max-free softmax, 4x unroll ----------------
// mode 1: relu + write bf16 hi/lo split; mode 0: write fp32 h
__global__ __launch_bounds__(256) void attn_kernel(
    const float* __restrict__ qkvs,
    const int* __restrict__ row_ptr,
    const int* __restrict__ col_src,
    float* __restrict__ hout,
    unsigned short* __restrict__ h_hi, unsigned short* __restrict__ h_lo,
    int n, int mode)
{
    int node = (int)((blockIdx.x * (size_t)blockDim.x + threadIdx.x) >> 6);
    int lane = threadIdx.x & 63;
    if (node >= n) return;
    float q = qkvs[(size_t)node * 256 + lane];
    int e0 = row_ptr[node], e1 = row_ptr[node + 1];
    float d0 = 0.f, d1 = 0.f, d2 = 0.f, d3 = 0.f;
    float a0 = 0.f, a1 = 0.f, a2 = 0.f, a3 = 0.f;
    int e = e0;
    for (; e + 3 < e1; e += 4) {
        int s0 = col_src[e], s1 = col_src[e + 1], s2 = col_src[e + 2], s3 = col_src[e + 3];
        const float* r0 = qkvs + (size_t)s0 * 256;
        const float* r1 = qkvs + (size_t)s1 * 256;
        const float* r2 = qkvs + (size_t)s2 * 256;
        const float* r3 = qkvs + (size_t)s3 * 256;
        float k0 = r0[64 + lane], k1 = r1[64 + lane], k2 = r2[64 + lane], k3 = r3[64 + lane];
        float v0 = r0[128 + lane], v1 = r1[128 + lane], v2 = r2[128 + lane], v3 = r3[128 + lane];
        float p0 = q * k0, p1 = q * k1, p2 = q * k2, p3 = q * k3;
        p0 += __shfl_xor(p0, 1, 64); p1 += __shfl_xor(p1, 1, 64);
        p2 += __shfl_xor(p2, 1, 64); p3 += __shfl_xor(p3, 1, 64);
        p0 += __shfl_xor(p0, 2, 64); p1 += __shfl_xor(p1, 2, 64);
        p2 += __shfl_xor(p2, 2, 64); p3 += __shfl_xor(p3, 2, 64);
        p0 += __shfl_xor(p0, 4, 64); p1 += __shfl_xor(p1, 4, 64);
        p2 += __shfl_xor(p2, 4, 64); p3 += __shfl_xor(p3, 4, 64);
        p0 += __shfl_xor(p0, 8, 64); p1 += __shfl_xor(p1, 8, 64);
        p2 += __shfl_xor(p2, 8, 64); p3 += __shfl_xor(p3, 8, 64);
        p0 = __expf(p0 * 0.25f); p1 = __expf(p1 * 0.25f);
        p2 = __expf(p2 * 0.25f); p3 = __expf(p3 * 0.25f);
        d0 += p0; a0 += p0 * v0;
        d1 += p1; a1 += p1 * v1;
        d2 += p2; a2 += p2 * v2;
        d3 += p3; a3 += p3 * v3;
    }
    for (; e < e1; ++e) {
        int s = col_src[e];
        const float* r = qkvs + (size_t)s * 256;
        float kk = r[64 + lane], vv = r[128 + lane];
        float p = q * kk;
        p += __shfl_xor(p, 1, 64);
        p += __shfl_xor(p, 2, 64);
        p += __shfl_xor(p, 4, 64);
        p += __shfl_xor(p, 8, 64);
        p = __expf(p * 0.25f);
        d0 += p; a0 += p * vv;
    }
    float denom = (d0 + d1) + (d2 + d3);
    float acc = (a0 + a1) + (a2 + a3);
    float outv = acc / (denom + 1e-16f) + qkvs[(size_t)node * 256 + 192 + lane];
    if (mode == 1) {
        outv = fmaxf(outv, 0.f);
        unsigned short h = f2bf_rne(outv);
        unsigned short l = f2bf_rne(outv - bf2f(h));
        h_hi[(size_t)node * 64 + lane] = h;
        h_lo[(size_t)node * 64 + lane] = l;
    } else {
        hout[(size_t)node * 64 + lane] = outv;
    }
}

// ---------------- pooling + head ----------------
__global__ void graph_ranges_kernel(const int* __restrict__ bm, int* __restrict__ gstart,
                                    int n, int g) {
    int t = blockIdx.x * blockDim.x + threadIdx.x;
    if (t > g) return;
    if (t == g) { gstart[g] = n; return; }
    int lo = 0, hi = n;
    while (lo < hi) { int mid = (lo + hi) >> 1; if (bm[mid] < t) lo = mid + 1; else hi = mid; }
    gstart[t] = lo;
}

__global__ __launch_bounds__(256) void pool_kernel(
    const float* __restrict__ h, const int* __restrict__ gstart,
    float* __restrict__ pooled)
{
    int g = blockIdx.x;
    int c = threadIdx.x & 63, sub = threadIdx.x >> 6;
    int s = gstart[g], e = gstart[g + 1];
    float sum = 0.f;
    for (int i = s + sub; i < e; i += 4) sum += h[(size_t)i * 64 + c];
    __shared__ float tmp[256];
    tmp[threadIdx.x] = sum;
    __syncthreads();
    if (sub == 0) {
        sum = tmp[c] + tmp[c + 64] + tmp[c + 128] + tmp[c + 192];
        int cnt = e - s;
        pooled[g * 64 + c] = sum / fmaxf((float)cnt, 1.0f);
    }
}

__global__ void head_kernel(const float* __restrict__ pooled,
                            const float* __restrict__ Wl, const float* __restrict__ bl,
                            float* __restrict__ out)
{
    int g = blockIdx.x;
    int lane = threadIdx.x;
    __shared__ float pl[64];
    pl[lane] = pooled[g * 64 + lane];
    __syncthreads();
    float logit = -INFINITY;
    if (lane < NCLS) {
        float acc = bl[lane];
        for (int k = 0; k < 64; ++k) acc += pl[k] * Wl[k * NCLS + lane];
        logit = acc;
    }
    float mx = logit;
    mx = fmaxf(mx, __shfl_xor(mx, 1, 64));
    mx = fmaxf(mx, __shfl_xor(mx, 2, 64));
    mx = fmaxf(mx, __shfl_xor(mx, 4, 64));
    mx = fmaxf(mx, __shfl_xor(mx, 8, 64));
    float ex = (lane < NCLS) ? __expf(logit - mx) : 0.f;
    float sm = ex;
    sm += __shfl_xor(sm, 1, 64);
    sm += __shfl_xor(sm, 2, 64);
    sm += __shfl_xor(sm, 4, 64);
    sm += __shfl_xor(sm, 8, 64);
    if (lane < NCLS) out[g * NCLS + lane] = ex / sm;
}

// ---------------- launch ----------------
extern "C" void kernel_launch(void* const* d_in, const int* in_sizes, int n_in,
                              void* d_out, int out_size, void* d_ws, size_t ws_size,
                              hipStream_t stream) {
    const float* x  = (const float*)d_in[0];
    const int*   ei = (const int*)d_in[1];
    const int*   bm = (const int*)d_in[2];
    const float* W1[4] = {(const float*)d_in[3], (const float*)d_in[5], (const float*)d_in[7], (const float*)d_in[9]};
    const float* B1[4] = {(const float*)d_in[4], (const float*)d_in[6], (const float*)d_in[8], (const float*)d_in[10]};
    const float* W2[4] = {(const float*)d_in[11], (const float*)d_in[13], (const float*)d_in[15], (const float*)d_in[17]};
    const float* B2[4] = {(const float*)d_in[12], (const float*)d_in[14], (const float*)d_in[16], (const float*)d_in[18]};
    const float* W3[4] = {(const float*)d_in[19], (const float*)d_in[21], (const float*)d_in[23], (const float*)d_in[25]};
    const float* B3[4] = {(const float*)d_in[20], (const float*)d_in[22], (const float*)d_in[24], (const float*)d_in[26]};
    const float* Wl = (const float*)d_in[27];
    const float* bl = (const float*)d_in[28];
    float* outp = (float*)d_out;

    // workspace layout
    float* qkvs   = (float*)d_ws;                               // NPAD*256
    float* hf     = qkvs + (size_t)NPAD * 256;                  // NPAD*64
    float* pooled = hf + (size_t)NPAD * 64;                     // NG*64
    unsigned short* xs_hi = (unsigned short*)(pooled + NG * 64);// NPAD*128
    unsigned short* xs_lo = xs_hi + (size_t)NPAD * 128;
    unsigned short* hs_hi = xs_lo + (size_t)NPAD * 128;         // NPAD*64
    unsigned short* hs_lo = hs_hi + (size_t)NPAD * 64;
    unsigned short* wt_hi = hs_lo + (size_t)NPAD * 64;          // 3 * 4*64*128
    unsigned short* wt_lo = wt_hi + 3 * 4 * 64 * 128;
    int* row_ptr = (int*)(wt_lo + 3 * 4 * 64 * 128);            // N+1
    int* fillp   = row_ptr + (N_NODES + 1);
    int* counts  = fillp + N_NODES;
    int* col_src = counts + N_NODES;
    int* gstart  = col_src + N_EDGES;

    const int* srcp = ei;
    const int* dstp = ei + N_EDGES;

    // CSR build
    hipMemsetAsync(counts, 0, N_NODES * sizeof(int), stream);
    hist_kernel<<<(N_EDGES + 255) / 256, 256, 0, stream>>>(dstp, counts, N_EDGES);
    scan_kernel<<<1, 1024, 0, stream>>>(counts, row_ptr, fillp, N_NODES);
    scatter_kernel<<<(N_EDGES + 255) / 256, 256, 0, stream>>>(srcp, dstp, fillp, col_src, N_EDGES);

    // conversions
    int n4x = N_NODES * F_IN / 4;
    split_kernel<<<(n4x + 255) / 256, 256, 0, stream>>>(x, xs_hi, xs_lo, n4x);
    wconv_kernel<<<(4 * 128 * 64 + 255) / 256, 256, 0, stream>>>(
        W1[0], W1[1], W1[2], W1[3], F_IN, wt_hi + 0 * 4 * 64 * 128, wt_lo + 0 * 4 * 64 * 128);
    wconv_kernel<<<(4 * 64 * 64 + 255) / 256, 256, 0, stream>>>(
        W2[0], W2[1], W2[2], W2[3], HC, wt_hi + 1 * 4 * 64 * 128, wt_lo + 1 * 4 * 64 * 128);
    wconv_kernel<<<(4 * 64 * 64 + 255) / 256, 256, 0, stream>>>(
        W3[0], W3[1], W3[2], W3[3], HC, wt_hi + 2 * 4 * 64 * 128, wt_lo + 2 * 4 * 64 * 128);

    dim3 ggrid((N_NODES + 63) / 64, 4);
    int agrid = (N_NODES + 3) / 4;
    size_t smem1 = (size_t)4 * 64 * F_IN * 2;   // 64 KB
    size_t smem2 = (size_t)4 * 64 * HC * 2;     // 32 KB

    // layer 1
    mfma_gemm_kernel<<<ggrid, 256, smem1, stream>>>(xs_hi, xs_lo,
        wt_hi + 0 * 4 * 64 * 128, wt_lo + 0 * 4 * 64 * 128,
        B1[0], B1[1], B1[2], B1[3], qkvs, N_NODES, F_IN);
    attn_kernel<<<agrid, 256, 0, stream>>>(qkvs, row_ptr, col_src, nullptr, hs_hi, hs_lo, N_NODES, 1);
    // layer 2
    mfma_gemm_kernel<<<ggrid, 256, smem2, stream>>>(hs_hi, hs_lo,
        wt_hi + 1 * 4 * 64 * 128, wt_lo + 1 * 4 * 64 * 128,
        B2[0], B2[1], B2[2], B2[3], qkvs, N_NODES, HC);
    attn_kernel<<<agrid, 256, 0, stream>>>(qkvs, row_ptr, col_src, nullptr, hs_hi, hs_lo, N_NODES, 1);
    // layer 3
    mfma_gemm_kernel<<<ggrid, 256, smem2, stream>>>(hs_hi, hs_lo,
        wt_hi + 2 * 4 * 64 * 128, wt_lo + 2 * 4 * 64 * 128,
        B3[0], B3[1], B3[2], B3[3], qkvs, N_NODES, HC);
    attn_kernel<<<agrid, 256, 0, stream>>>(qkvs, row_ptr, col_src, hf, nullptr, nullptr, N_NODES, 0);

    // pooling + head
    graph_ranges_kernel<<<1, 256, 0, stream>>>(bm, gstart, N_NODES, NG);
    pool_kernel<<<NG, 256, 0, stream>>>(hf, gstart, pooled);
    head_kernel<<<NG, 64, 0, stream>>>(pooled, Wl, bl, outp);
}

// Round 3
// 387.173 us; speedup vs baseline: 1.9710x; 1.1833x over previous
//
#include <hip/hip_runtime.h>
#include <hip/hip_fp16.h>
#include <math.h>

#define N_NODES 50000
#define NPAD    50048
#define N_EDGES 800000
#define F_IN    128
#define HC      64
#define NG      128
#define NCLS    10
#define NXT     782      // ceil(N_NODES/64) row tiles
#define XCHUNK  98       // ceil(NXT/8) tiles per XCD

typedef __attribute__((ext_vector_type(8))) short bfrag;   // 8 bf16 (4 VGPR)
typedef __attribute__((ext_vector_type(4))) float f32x4;

__device__ __forceinline__ unsigned short f2bf_rne(float f) {
    unsigned u = __float_as_uint(f);
    unsigned r = u + 0x7FFF + ((u >> 16) & 1);
    return (unsigned short)(r >> 16);
}
__device__ __forceinline__ float bf2f(unsigned short h) {
    return __uint_as_float(((unsigned)h) << 16);
}

// ---------------- CSR build ----------------
__global__ void hist_kernel(const int* __restrict__ dst, int* __restrict__ counts, int e) {
    int t = blockIdx.x * blockDim.x + threadIdx.x;
    if (t < e) atomicAdd(&counts[dst[t]], 1);
}

// 3-phase scan: A) per-block (256) local scan, B) scan of block sums, C) add + emit
__global__ __launch_bounds__(256) void scanA_kernel(const int* __restrict__ counts,
                                                    int* __restrict__ excl,
                                                    int* __restrict__ bsum, int n) {
    int tid = threadIdx.x, bid = blockIdx.x;
    int i = bid * 256 + tid;
    int v = (i < n) ? counts[i] : 0;
    int lane = tid & 63, wid = tid >> 6;
    int sc = v;
    #pragma unroll
    for (int off = 1; off < 64; off <<= 1) {
        int t = __shfl_up(sc, off, 64);
        if (lane >= off) sc += t;
    }
    __shared__ int ws[4];
    if (lane == 63) ws[wid] = sc;
    __syncthreads();
    int add = 0;
    #pragma unroll
    for (int k = 0; k < 4; ++k) if (k < wid) add += ws[k];
    int incl = sc + add;
    if (i < n) excl[i] = incl - v;
    if (tid == 255) bsum[bid] = incl;
}

__global__ __launch_bounds__(256) void scanB_kernel(const int* __restrict__ bsum,
                                                    int* __restrict__ boff, int nb) {
    int tid = threadIdx.x;
    int v = (tid < nb) ? bsum[tid] : 0;
    int lane = tid & 63, wid = tid >> 6;
    int sc = v;
    #pragma unroll
    for (int off = 1; off < 64; off <<= 1) {
        int t = __shfl_up(sc, off, 64);
        if (lane >= off) sc += t;
    }
    __shared__ int ws[4];
    if (lane == 63) ws[wid] = sc;
    __syncthreads();
    int add = 0;
    #pragma unroll
    for (int k = 0; k < 4; ++k) if (k < wid) add += ws[k];
    if (tid < nb) boff[tid] = sc + add - v;
}

__global__ __launch_bounds__(256) void scanC_kernel(const int* __restrict__ excl,
                                                    const int* __restrict__ boff,
                                                    int* __restrict__ row_ptr,
                                                    int* __restrict__ fillp, int n) {
    int i = blockIdx.x * 256 + threadIdx.x;
    if (i < n) {
        int r = excl[i] + boff[i >> 8];
        row_ptr[i] = r;
        fillp[i] = r;
    }
    if (i == n) row_ptr[n] = N_EDGES;
}

__global__ void scatter_kernel(const int* __restrict__ src, const int* __restrict__ dst,
                               int* __restrict__ fillp, int* __restrict__ col_src, int e) {
    int t = blockIdx.x * blockDim.x + threadIdx.x;
    if (t < e) {
        int pos = atomicAdd(&fillp[dst[t]], 1);
        col_src[pos] = src[t];
    }
}

// ---------------- fp32 -> bf16 hi/lo split (x input) ----------------
__global__ void split_kernel(const float* __restrict__ in, unsigned short* __restrict__ hi,
                             unsigned short* __restrict__ lo, int n4) {
    int t = blockIdx.x * blockDim.x + threadIdx.x;
    if (t >= n4) return;
    float4 f = ((const float4*)in)[t];
    unsigned short h[4], l[4];
    float ff[4] = {f.x, f.y, f.z, f.w};
    #pragma unroll
    for (int i = 0; i < 4; ++i) {
        h[i] = f2bf_rne(ff[i]);
        l[i] = f2bf_rne(ff[i] - bf2f(h[i]));
    }
    ((ushort4*)hi)[t] = make_ushort4(h[0], h[1], h[2], h[3]);
    ((ushort4*)lo)[t] = make_ushort4(l[0], l[1], l[2], l[3]);
}

// ---------------- W [K][64] fp32 -> transposed bf16 hi/lo [mat][64][K] ----------------
__global__ void wconv_kernel(const float* __restrict__ W0, const float* __restrict__ W1,
                             const float* __restrict__ W2, const float* __restrict__ W3,
                             int K, unsigned short* __restrict__ wt_hi,
                             unsigned short* __restrict__ wt_lo) {
    int t = blockIdx.x * blockDim.x + threadIdx.x;
    int per = K * 64;
    if (t >= 4 * per) return;
    int mat = t / per, r = t - mat * per;
    int k = r >> 6, c = r & 63;
    const float* W = (mat == 0) ? W0 : (mat == 1) ? W1 : (mat == 2) ? W2 : W3;
    float f = W[k * 64 + c];
    unsigned short h = f2bf_rne(f);
    unsigned short l = f2bf_rne(f - bf2f(h));
    int idx = mat * per + c * K + k;
    wt_hi[idx] = h;
    wt_lo[idx] = l;
}

// ---------------- split-bf16 MFMA GEMM ----------------
// y=0 -> qf fp32, y=3 -> sf fp32, y=1 -> kvp low half (k fp16), y=2 -> kvp high half (v fp16)
// 1-D grid XCD-swizzled so the 4 y-variants of one row-tile run back-to-back on one XCD.
__global__ __launch_bounds__(256) void mfma_gemm_kernel(
    const unsigned short* __restrict__ A_hi, const unsigned short* __restrict__ A_lo,
    const unsigned short* __restrict__ Wt_hi, const unsigned short* __restrict__ Wt_lo,
    const float* __restrict__ b0, const float* __restrict__ b1,
    const float* __restrict__ b2, const float* __restrict__ b3,
    float* __restrict__ qf, float* __restrict__ sf, unsigned short* __restrict__ kvp16,
    int M, int K)
{
    int bid = blockIdx.x;
    int xcd = bid & 7;
    int slot = bid >> 3;
    int xt = xcd * XCHUNK + (slot >> 2);
    int y = slot & 3;
    if (xt >= NXT) return;
    int row0 = xt * 64;

    extern __shared__ char smem[];
    const int tileU = 64 * K;
    unsigned short* sA_hi = (unsigned short*)smem;
    unsigned short* sA_lo = sA_hi + tileU;
    unsigned short* sB_hi = sA_lo + tileU;
    unsigned short* sB_lo = sB_hi + tileU;

    int tid = threadIdx.x;
    int cpr = K >> 3;
    int total = 64 * cpr;
    const bfrag* gAh = (const bfrag*)(A_hi + (size_t)row0 * K);
    const bfrag* gAl = (const bfrag*)(A_lo + (size_t)row0 * K);
    const bfrag* gBh = (const bfrag*)(Wt_hi + (size_t)y * tileU);
    const bfrag* gBl = (const bfrag*)(Wt_lo + (size_t)y * tileU);
    for (int t = tid; t < total; t += 256) {
        int row = t / cpr, cs = t - row * cpr;
        int dstB = row * (K * 2) + ((cs * 16) ^ ((row & 7) << 4));
        *(bfrag*)((char*)sA_hi + dstB) = gAh[t];
        *(bfrag*)((char*)sA_lo + dstB) = gAl[t];
        *(bfrag*)((char*)sB_hi + dstB) = gBh[t];
        *(bfrag*)((char*)sB_lo + dstB) = gBl[t];
    }
    __syncthreads();

    int w = tid >> 6, lane = tid & 63, lr = lane & 15, kq = lane >> 4;
    f32x4 acc[4];
    #pragma unroll
    for (int f = 0; f < 4; ++f) acc[f] = (f32x4){0.f, 0.f, 0.f, 0.f};

    int arow = w * 16 + lr;
    int abase = arow * (K * 2);
    int aswz = (arow & 7) << 4;
    for (int ks = 0; ks < K; ks += 32) {
        int kb = ks * 2 + kq * 16;
        bfrag ah = *(const bfrag*)((const char*)sA_hi + abase + (kb ^ aswz));
        bfrag al = *(const bfrag*)((const char*)sA_lo + abase + (kb ^ aswz));
        #pragma unroll
        for (int f = 0; f < 4; ++f) {
            int brow = f * 16 + lr;
            int boff = brow * (K * 2) + (kb ^ ((brow & 7) << 4));
            bfrag bh = *(const bfrag*)((const char*)sB_hi + boff);
            bfrag bl = *(const bfrag*)((const char*)sB_lo + boff);
            acc[f] = __builtin_amdgcn_mfma_f32_16x16x32_bf16(ah, bh, acc[f], 0, 0, 0);
            acc[f] = __builtin_amdgcn_mfma_f32_16x16x32_bf16(ah, bl, acc[f], 0, 0, 0);
            acc[f] = __builtin_amdgcn_mfma_f32_16x16x32_bf16(al, bh, acc[f], 0, 0, 0);
        }
    }

    const float* bias = (y == 0) ? b0 : (y == 1) ? b1 : (y == 2) ? b2 : b3;
    if (y == 0 || y == 3) {
        float* dst = (y == 0) ? qf : sf;
        #pragma unroll
        for (int f = 0; f < 4; ++f) {
            float bv = bias[f * 16 + lr];
            #pragma unroll
            for (int r = 0; r < 4; ++r) {
                int gr = row0 + w * 16 + kq * 4 + r;
                if (gr < M) dst[(size_t)gr * 64 + f * 16 + lr] = acc[f][r] + bv;
            }
        }
    } else {
        int sub = (y == 1) ? 0 : 1;   // k in low half, v in high half
        #pragma unroll
        for (int f = 0; f < 4; ++f) {
            float bv = bias[f * 16 + lr];
            #pragma unroll
            for (int r = 0; r < 4; ++r) {
                int gr = row0 + w * 16 + kq * 4 + r;
                if (gr < M) {
                    unsigned short hv = __half_as_ushort(__float2half_rn(acc[f][r] + bv));
                    kvp16[((size_t)gr * 64 + f * 16 + lr) * 2 + sub] = hv;
                }
            }
        }
    }
}

// ---------------- attention: wave per dst node, packed fp16 kv gather ----------------
__global__ __launch_bounds__(256) void attn_kernel(
    const float* __restrict__ qf, const float* __restrict__ sf,
    const unsigned* __restrict__ kvp,
    const int* __restrict__ row_ptr, const int* __restrict__ col_src,
    float* __restrict__ hout,
    unsigned short* __restrict__ h_hi, unsigned short* __restrict__ h_lo,
    int n, int mode)
{
    int node = (int)((blockIdx.x * (size_t)blockDim.x + threadIdx.x) >> 6);
    int lane = threadIdx.x & 63;
    if (node >= n) return;
    float q = qf[(size_t)node * 64 + lane];
    int e0 = row_ptr[node], e1 = row_ptr[node + 1];
    float d0 = 0.f, d1 = 0.f, d2 = 0.f, d3 = 0.f;
    float a0 = 0.f, a1 = 0.f, a2 = 0.f, a3 = 0.f;
    int e = e0;
    for (; e + 3 < e1; e += 4) {
        int s0 = col_src[e], s1 = col_src[e + 1], s2 = col_src[e + 2], s3 = col_src[e + 3];
        unsigned u0 = kvp[(size_t)s0 * 64 + lane];
        unsigned u1 = kvp[(size_t)s1 * 64 + lane];
        unsigned u2 = kvp[(size_t)s2 * 64 + lane];
        unsigned u3 = kvp[(size_t)s3 * 64 + lane];
        __half2 h0 = *reinterpret_cast<__half2*>(&u0);
        __half2 h1 = *reinterpret_cast<__half2*>(&u1);
        __half2 h2 = *reinterpret_cast<__half2*>(&u2);
        __half2 h3 = *reinterpret_cast<__half2*>(&u3);
        float p0 = q * __low2float(h0), p1 = q * __low2float(h1);
        float p2 = q * __low2float(h2), p3 = q * __low2float(h3);
        p0 += __shfl_xor(p0, 1, 64); p1 += __shfl_xor(p1, 1, 64);
        p2 += __shfl_xor(p2, 1, 64); p3 += __shfl_xor(p3, 1, 64);
        p0 += __shfl_xor(p0, 2, 64); p1 += __shfl_xor(p1, 2, 64);
        p2 += __shfl_xor(p2, 2, 64); p3 += __shfl_xor(p3, 2, 64);
        p0 += __shfl_xor(p0, 4, 64); p1 += __shfl_xor(p1, 4, 64);
        p2 += __shfl_xor(p2, 4, 64); p3 += __shfl_xor(p3, 4, 64);
        p0 += __shfl_xor(p0, 8, 64); p1 += __shfl_xor(p1, 8, 64);
        p2 += __shfl_xor(p2, 8, 64); p3 += __shfl_xor(p3, 8, 64);
        p0 = __expf(p0 * 0.25f); p1 = __expf(p1 * 0.25f);
        p2 = __expf(p2 * 0.25f); p3 = __expf(p3 * 0.25f);
        d0 += p0; a0 += p0 * __high2float(h0);
        d1 += p1; a1 += p1 * __high2float(h1);
        d2 += p2; a2 += p2 * __high2float(h2);
        d3 += p3; a3 += p3 * __high2float(h3);
    }
    for (; e < e1; ++e) {
        int s = col_src[e];
        unsigned u = kvp[(size_t)s * 64 + lane];
        __half2 h = *reinterpret_cast<__half2*>(&u);
        float p = q * __low2float(h);
        p += __shfl_xor(p, 1, 64);
        p += __shfl_xor(p, 2, 64);
        p += __shfl_xor(p, 4, 64);
        p += __shfl_xor(p, 8, 64);
        p = __expf(p * 0.25f);
        d0 += p; a0 += p * __high2float(h);
    }
    float denom = (d0 + d1) + (d2 + d3);
    float acc = (a0 + a1) + (a2 + a3);
    float outv = acc / (denom + 1e-16f) + sf[(size_t)node * 64 + lane];
    if (mode == 1) {
        outv = fmaxf(outv, 0.f);
        unsigned short h = f2bf_rne(outv);
        unsigned short l = f2bf_rne(outv - bf2f(h));
        h_hi[(size_t)node * 64 + lane] = h;
        h_lo[(size_t)node * 64 + lane] = l;
    } else {
        hout[(size_t)node * 64 + lane] = outv;
    }
}

// ---------------- pooling + head ----------------
__global__ void graph_ranges_kernel(const int* __restrict__ bm, int* __restrict__ gstart,
                                    int n, int g) {
    int t = blockIdx.x * blockDim.x + threadIdx.x;
    if (t > g) return;
    if (t == g) { gstart[g] = n; return; }
    int lo = 0, hi = n;
    while (lo < hi) { int mid = (lo + hi) >> 1; if (bm[mid] < t) lo = mid + 1; else hi = mid; }
    gstart[t] = lo;
}

__global__ __launch_bounds__(256) void pool_kernel(
    const float* __restrict__ h, const int* __restrict__ gstart,
    float* __restrict__ pooled)
{
    int g = blockIdx.x;
    int c = threadIdx.x & 63, sub = threadIdx.x >> 6;
    int s = gstart[g], e = gstart[g + 1];
    float sum = 0.f;
    for (int i = s + sub; i < e; i += 4) sum += h[(size_t)i * 64 + c];
    __shared__ float tmp[256];
    tmp[threadIdx.x] = sum;
    __syncthreads();
    if (sub == 0) {
        sum = tmp[c] + tmp[c + 64] + tmp[c + 128] + tmp[c + 192];
        int cnt = e - s;
        pooled[g * 64 + c] = sum / fmaxf((float)cnt, 1.0f);
    }
}

__global__ void head_kernel(const float* __restrict__ pooled,
                            const float* __restrict__ Wl, const float* __restrict__ bl,
                            float* __restrict__ out)
{
    int g = blockIdx.x;
    int lane = threadIdx.x;
    __shared__ float pl[64];
    pl[lane] = pooled[g * 64 + lane];
    __syncthreads();
    float logit = -INFINITY;
    if (lane < NCLS) {
        float acc = bl[lane];
        for (int k = 0; k < 64; ++k) acc += pl[k] * Wl[k * NCLS + lane];
        logit = acc;
    }
    float mx = logit;
    mx = fmaxf(mx, __shfl_xor(mx, 1, 64));
    mx = fmaxf(mx, __shfl_xor(mx, 2, 64));
    mx = fmaxf(mx, __shfl_xor(mx, 4, 64));
    mx = fmaxf(mx, __shfl_xor(mx, 8, 64));
    float ex = (lane < NCLS) ? __expf(logit - mx) : 0.f;
    float sm = ex;
    sm += __shfl_xor(sm, 1, 64);
    sm += __shfl_xor(sm, 2, 64);
    sm += __shfl_xor(sm, 4, 64);
    sm += __shfl_xor(sm, 8, 64);
    if (lane < NCLS) out[g * NCLS + lane] = ex / sm;
}

// ---------------- launch ----------------
extern "C" void kernel_launch(void* const* d_in, const int* in_sizes, int n_in,
                              void* d_out, int out_size, void* d_ws, size_t ws_size,
                              hipStream_t stream) {
    const float* x  = (const float*)d_in[0];
    const int*   ei = (const int*)d_in[1];
    const int*   bm = (const int*)d_in[2];
    const float* W1[4] = {(const float*)d_in[3], (const float*)d_in[5], (const float*)d_in[7], (const float*)d_in[9]};
    const float* B1[4] = {(const float*)d_in[4], (const float*)d_in[6], (const float*)d_in[8], (const float*)d_in[10]};
    const float* W2[4] = {(const float*)d_in[11], (const float*)d_in[13], (const float*)d_in[15], (const float*)d_in[17]};
    const float* B2[4] = {(const float*)d_in[12], (const float*)d_in[14], (const float*)d_in[16], (const float*)d_in[18]};
    const float* W3[4] = {(const float*)d_in[19], (const float*)d_in[21], (const float*)d_in[23], (const float*)d_in[25]};
    const float* B3[4] = {(const float*)d_in[20], (const float*)d_in[22], (const float*)d_in[24], (const float*)d_in[26]};
    const float* Wl = (const float*)d_in[27];
    const float* bl = (const float*)d_in[28];
    float* outp = (float*)d_out;

    // workspace layout
    float* qf     = (float*)d_ws;                                // NPAD*64
    float* sf     = qf + (size_t)NPAD * 64;                      // NPAD*64
    float* hf     = sf + (size_t)NPAD * 64;                      // NPAD*64
    float* pooled = hf + (size_t)NPAD * 64;                      // NG*64
    unsigned* kvp = (unsigned*)(pooled + NG * 64);               // NPAD*64 u32
    unsigned short* xs_hi = (unsigned short*)(kvp + (size_t)NPAD * 64); // NPAD*128
    unsigned short* xs_lo = xs_hi + (size_t)NPAD * 128;
    unsigned short* hs_hi = xs_lo + (size_t)NPAD * 128;          // NPAD*64
    unsigned short* hs_lo = hs_hi + (size_t)NPAD * 64;
    unsigned short* wt_hi = hs_lo + (size_t)NPAD * 64;           // 3 * 4*64*128
    unsigned short* wt_lo = wt_hi + 3 * 4 * 64 * 128;
    int* row_ptr = (int*)(wt_lo + 3 * 4 * 64 * 128);             // N+1
    int* fillp   = row_ptr + (N_NODES + 1);
    int* counts  = fillp + N_NODES;
    int* excl    = counts + N_NODES;                             // N
    int* bsum    = excl + N_NODES;                               // 256
    int* boff    = bsum + 256;                                   // 256
    int* col_src = boff + 256;                                   // E
    int* gstart  = col_src + N_EDGES;                            // NG+1

    const int* srcp = ei;
    const int* dstp = ei + N_EDGES;

    // CSR build
    hipMemsetAsync(counts, 0, N_NODES * sizeof(int), stream);
    hist_kernel<<<(N_EDGES + 255) / 256, 256, 0, stream>>>(dstp, counts, N_EDGES);
    scanA_kernel<<<196, 256, 0, stream>>>(counts, excl, bsum, N_NODES);
    scanB_kernel<<<1, 256, 0, stream>>>(bsum, boff, 196);
    scanC_kernel<<<196, 256, 0, stream>>>(excl, boff, row_ptr, fillp, N_NODES);
    scatter_kernel<<<(N_EDGES + 255) / 256, 256, 0, stream>>>(srcp, dstp, fillp, col_src, N_EDGES);

    // conversions
    int n4x = N_NODES * F_IN / 4;
    split_kernel<<<(n4x + 255) / 256, 256, 0, stream>>>(x, xs_hi, xs_lo, n4x);
    wconv_kernel<<<(4 * 128 * 64 + 255) / 256, 256, 0, stream>>>(
        W1[0], W1[1], W1[2], W1[3], F_IN, wt_hi + 0 * 4 * 64 * 128, wt_lo + 0 * 4 * 64 * 128);
    wconv_kernel<<<(4 * 64 * 64 + 255) / 256, 256, 0, stream>>>(
        W2[0], W2[1], W2[2], W2[3], HC, wt_hi + 1 * 4 * 64 * 128, wt_lo + 1 * 4 * 64 * 128);
    wconv_kernel<<<(4 * 64 * 64 + 255) / 256, 256, 0, stream>>>(
        W3[0], W3[1], W3[2], W3[3], HC, wt_hi + 2 * 4 * 64 * 128, wt_lo + 2 * 4 * 64 * 128);

    int ggrid = 8 * XCHUNK * 4;               // 3136 blocks, XCD-swizzled inside
    int agrid = (N_NODES + 3) / 4;
    size_t smem1 = (size_t)4 * 64 * F_IN * 2; // 64 KB
    size_t smem2 = (size_t)4 * 64 * HC * 2;   // 32 KB

    // layer 1
    mfma_gemm_kernel<<<ggrid, 256, smem1, stream>>>(xs_hi, xs_lo,
        wt_hi + 0 * 4 * 64 * 128, wt_lo + 0 * 4 * 64 * 128,
        B1[0], B1[1], B1[2], B1[3], qf, sf, (unsigned short*)kvp, N_NODES, F_IN);
    attn_kernel<<<agrid, 256, 0, stream>>>(qf, sf, kvp, row_ptr, col_src, nullptr, hs_hi, hs_lo, N_NODES, 1);
    // layer 2
    mfma_gemm_kernel<<<ggrid, 256, smem2, stream>>>(hs_hi, hs_lo,
        wt_hi + 1 * 4 * 64 * 128, wt_lo + 1 * 4 * 64 * 128,
        B2[0], B2[1], B2[2], B2[3], qf, sf, (unsigned short*)kvp, N_NODES, HC);
    attn_kernel<<<agrid, 256, 0, stream>>>(qf, sf, kvp, row_ptr, col_src, nullptr, hs_hi, hs_lo, N_NODES, 1);
    // layer 3
    mfma_gemm_kernel<<<ggrid, 256, smem2, stream>>>(hs_hi, hs_lo,
        wt_hi + 2 * 4 * 64 * 128, wt_lo + 2 * 4 * 64 * 128,
        B3[0], B3[1], B3[2], B3[3], qf, sf, (unsigned short*)kvp, N_NODES, HC);
    attn_kernel<<<agrid, 256, 0, stream>>>(qf, sf, kvp, row_ptr, col_src, hf, nullptr, nullptr, N_NODES, 0);

    // pooling + head
    graph_ranges_kernel<<<1, 256, 0, stream>>>(bm, gstart, N_NODES, NG);
    pool_kernel<<<NG, 256, 0, stream>>>(hf, gstart, pooled);
    head_kernel<<<NG, 64, 0, stream>>>(pooled, Wl, bl, outp);
}

// Round 4
// 342.116 us; speedup vs baseline: 2.2306x; 1.1317x over previous
//
#include <hip/hip_runtime.h>
#include <hip/hip_fp16.h>
#include <math.h>

#define N_NODES 50000
#define NPAD    50048
#define N_EDGES 800000
#define F_IN    128
#define HC      64
#define NG      128
#define NCLS    10
#define NXT     782      // ceil(N_NODES/64) row tiles
#define XCHUNK  98       // ceil(NXT/8) tiles per XCD

typedef __attribute__((ext_vector_type(8))) short bfrag;   // 8 bf16 (4 VGPR)
typedef __attribute__((ext_vector_type(4))) float f32x4;
typedef _Float16 half2v __attribute__((ext_vector_type(2)));

__device__ __forceinline__ unsigned short f2bf_rne(float f) {
    unsigned u = __float_as_uint(f);
    unsigned r = u + 0x7FFF + ((u >> 16) & 1);
    return (unsigned short)(r >> 16);
}
__device__ __forceinline__ float bf2f(unsigned short h) {
    return __uint_as_float(((unsigned)h) << 16);
}

__device__ __forceinline__ float fdot2_acc(unsigned a, unsigned b, float c) {
#if __has_builtin(__builtin_amdgcn_fdot2)
    half2v ha, hb;
    __builtin_memcpy(&ha, &a, 4);
    __builtin_memcpy(&hb, &b, 4);
    return __builtin_amdgcn_fdot2(ha, hb, c, false);
#else
    __half2 ha = *(__half2*)&a, hb = *(__half2*)&b;
    return c + __low2float(ha) * __low2float(hb) + __high2float(ha) * __high2float(hb);
#endif
}

// ---------------- CSR build ----------------
__global__ void hist_kernel(const int* __restrict__ dst, int* __restrict__ counts, int e) {
    int t = blockIdx.x * blockDim.x + threadIdx.x;
    if (t < e) atomicAdd(&counts[dst[t]], 1);
}

__global__ __launch_bounds__(256) void scanA_kernel(const int* __restrict__ counts,
                                                    int* __restrict__ excl,
                                                    int* __restrict__ bsum, int n) {
    int tid = threadIdx.x, bid = blockIdx.x;
    int i = bid * 256 + tid;
    int v = (i < n) ? counts[i] : 0;
    int lane = tid & 63, wid = tid >> 6;
    int sc = v;
    #pragma unroll
    for (int off = 1; off < 64; off <<= 1) {
        int t = __shfl_up(sc, off, 64);
        if (lane >= off) sc += t;
    }
    __shared__ int ws[4];
    if (lane == 63) ws[wid] = sc;
    __syncthreads();
    int add = 0;
    #pragma unroll
    for (int k = 0; k < 4; ++k) if (k < wid) add += ws[k];
    int incl = sc + add;
    if (i < n) excl[i] = incl - v;
    if (tid == 255) bsum[bid] = incl;
}

__global__ __launch_bounds__(256) void scanB_kernel(const int* __restrict__ bsum,
                                                    int* __restrict__ boff, int nb) {
    int tid = threadIdx.x;
    int v = (tid < nb) ? bsum[tid] : 0;
    int lane = tid & 63, wid = tid >> 6;
    int sc = v;
    #pragma unroll
    for (int off = 1; off < 64; off <<= 1) {
        int t = __shfl_up(sc, off, 64);
        if (lane >= off) sc += t;
    }
    __shared__ int ws[4];
    if (lane == 63) ws[wid] = sc;
    __syncthreads();
    int add = 0;
    #pragma unroll
    for (int k = 0; k < 4; ++k) if (k < wid) add += ws[k];
    if (tid < nb) boff[tid] = sc + add - v;
}

__global__ __launch_bounds__(256) void scanC_kernel(const int* __restrict__ excl,
                                                    const int* __restrict__ boff,
                                                    int* __restrict__ row_ptr,
                                                    int* __restrict__ fillp, int n) {
    int i = blockIdx.x * 256 + threadIdx.x;
    if (i < n) {
        int r = excl[i] + boff[i >> 8];
        row_ptr[i] = r;
        fillp[i] = r;
    }
    if (i == n) row_ptr[n] = N_EDGES;
}

__global__ void scatter_kernel(const int* __restrict__ src, const int* __restrict__ dst,
                               int* __restrict__ fillp, int* __restrict__ col_src, int e) {
    int t = blockIdx.x * blockDim.x + threadIdx.x;
    if (t < e) {
        int pos = atomicAdd(&fillp[dst[t]], 1);
        col_src[pos] = src[t];
    }
}

// ---------------- fp32 -> bf16 hi/lo split (x input) ----------------
__global__ void split_kernel(const float* __restrict__ in, unsigned short* __restrict__ hi,
                             unsigned short* __restrict__ lo, int n4) {
    int t = blockIdx.x * blockDim.x + threadIdx.x;
    if (t >= n4) return;
    float4 f = ((const float4*)in)[t];
    unsigned short h[4], l[4];
    float ff[4] = {f.x, f.y, f.z, f.w};
    #pragma unroll
    for (int i = 0; i < 4; ++i) {
        h[i] = f2bf_rne(ff[i]);
        l[i] = f2bf_rne(ff[i] - bf2f(h[i]));
    }
    ((ushort4*)hi)[t] = make_ushort4(h[0], h[1], h[2], h[3]);
    ((ushort4*)lo)[t] = make_ushort4(l[0], l[1], l[2], l[3]);
}

// ---------------- W [K][64] fp32 -> transposed bf16 hi/lo [mat][64][K] ----------------
__global__ void wconv_kernel(const float* __restrict__ W0, const float* __restrict__ W1,
                             const float* __restrict__ W2, const float* __restrict__ W3,
                             int K, unsigned short* __restrict__ wt_hi,
                             unsigned short* __restrict__ wt_lo) {
    int t = blockIdx.x * blockDim.x + threadIdx.x;
    int per = K * 64;
    if (t >= 4 * per) return;
    int mat = t / per, r = t - mat * per;
    int k = r >> 6, c = r & 63;
    const float* W = (mat == 0) ? W0 : (mat == 1) ? W1 : (mat == 2) ? W2 : W3;
    float f = W[k * 64 + c];
    unsigned short h = f2bf_rne(f);
    unsigned short l = f2bf_rne(f - bf2f(h));
    int idx = mat * per + c * K + k;
    wt_hi[idx] = h;
    wt_lo[idx] = l;
}

// ---------------- split-bf16 MFMA GEMM ----------------
// y=0 -> qp16 fp16, y=3 -> sf fp32, y=1 -> kvpk k-block fp16, y=2 -> kvpk v-block fp16
__global__ __launch_bounds__(256) void mfma_gemm_kernel(
    const unsigned short* __restrict__ A_hi, const unsigned short* __restrict__ A_lo,
    const unsigned short* __restrict__ Wt_hi, const unsigned short* __restrict__ Wt_lo,
    const float* __restrict__ b0, const float* __restrict__ b1,
    const float* __restrict__ b2, const float* __restrict__ b3,
    unsigned short* __restrict__ qp16, float* __restrict__ sf,
    unsigned short* __restrict__ kvpk,
    int M, int K)
{
    int bid = blockIdx.x;
    int xcd = bid & 7;
    int slot = bid >> 3;
    int xt = xcd * XCHUNK + (slot >> 2);
    int y = slot & 3;
    if (xt >= NXT) return;
    int row0 = xt * 64;

    extern __shared__ char smem[];
    const int tileU = 64 * K;
    unsigned short* sA_hi = (unsigned short*)smem;
    unsigned short* sA_lo = sA_hi + tileU;
    unsigned short* sB_hi = sA_lo + tileU;
    unsigned short* sB_lo = sB_hi + tileU;

    int tid = threadIdx.x;
    int cpr = K >> 3;
    int total = 64 * cpr;
    const bfrag* gAh = (const bfrag*)(A_hi + (size_t)row0 * K);
    const bfrag* gAl = (const bfrag*)(A_lo + (size_t)row0 * K);
    const bfrag* gBh = (const bfrag*)(Wt_hi + (size_t)y * tileU);
    const bfrag* gBl = (const bfrag*)(Wt_lo + (size_t)y * tileU);
    for (int t = tid; t < total; t += 256) {
        int row = t / cpr, cs = t - row * cpr;
        int dstB = row * (K * 2) + ((cs * 16) ^ ((row & 7) << 4));
        *(bfrag*)((char*)sA_hi + dstB) = gAh[t];
        *(bfrag*)((char*)sA_lo + dstB) = gAl[t];
        *(bfrag*)((char*)sB_hi + dstB) = gBh[t];
        *(bfrag*)((char*)sB_lo + dstB) = gBl[t];
    }
    __syncthreads();

    int w = tid >> 6, lane = tid & 63, lr = lane & 15, kq = lane >> 4;
    f32x4 acc[4];
    #pragma unroll
    for (int f = 0; f < 4; ++f) acc[f] = (f32x4){0.f, 0.f, 0.f, 0.f};

    int arow = w * 16 + lr;
    int abase = arow * (K * 2);
    int aswz = (arow & 7) << 4;
    for (int ks = 0; ks < K; ks += 32) {
        int kb = ks * 2 + kq * 16;
        bfrag ah = *(const bfrag*)((const char*)sA_hi + abase + (kb ^ aswz));
        bfrag al = *(const bfrag*)((const char*)sA_lo + abase + (kb ^ aswz));
        #pragma unroll
        for (int f = 0; f < 4; ++f) {
            int brow = f * 16 + lr;
            int boff = brow * (K * 2) + (kb ^ ((brow & 7) << 4));
            bfrag bh = *(const bfrag*)((const char*)sB_hi + boff);
            bfrag bl = *(const bfrag*)((const char*)sB_lo + boff);
            acc[f] = __builtin_amdgcn_mfma_f32_16x16x32_bf16(ah, bh, acc[f], 0, 0, 0);
            acc[f] = __builtin_amdgcn_mfma_f32_16x16x32_bf16(ah, bl, acc[f], 0, 0, 0);
            acc[f] = __builtin_amdgcn_mfma_f32_16x16x32_bf16(al, bh, acc[f], 0, 0, 0);
        }
    }

    const float* bias = (y == 0) ? b0 : (y == 1) ? b1 : (y == 2) ? b2 : b3;
    if (y == 3) {
        #pragma unroll
        for (int f = 0; f < 4; ++f) {
            float bv = bias[f * 16 + lr];
            #pragma unroll
            for (int r = 0; r < 4; ++r) {
                int gr = row0 + w * 16 + kq * 4 + r;
                if (gr < M) sf[(size_t)gr * 64 + f * 16 + lr] = acc[f][r] + bv;
            }
        }
    } else if (y == 0) {
        #pragma unroll
        for (int f = 0; f < 4; ++f) {
            float bv = bias[f * 16 + lr];
            #pragma unroll
            for (int r = 0; r < 4; ++r) {
                int gr = row0 + w * 16 + kq * 4 + r;
                if (gr < M)
                    qp16[(size_t)gr * 64 + f * 16 + lr] =
                        __half_as_ushort(__float2half_rn(acc[f][r] + bv));
            }
        }
    } else {
        int off = (y == 1) ? 0 : 64;   // k-block then v-block
        #pragma unroll
        for (int f = 0; f < 4; ++f) {
            float bv = bias[f * 16 + lr];
            #pragma unroll
            for (int r = 0; r < 4; ++r) {
                int gr = row0 + w * 16 + kq * 4 + r;
                if (gr < M)
                    kvpk[(size_t)gr * 128 + off + f * 16 + lr] =
                        __half_as_ushort(__float2half_rn(acc[f][r] + bv));
            }
        }
    }
}

// ---------------- attention: wave per dst node, lane = (head, edge-slot) ----------------
// qp [N][64] fp16 (d = h*16+c); kv4 [N][16] uint4: k chans 0..63 then v chans 0..63.
__global__ __launch_bounds__(256) void attn_kernel(
    const unsigned short* __restrict__ qp, const float* __restrict__ sf,
    const uint4* __restrict__ kv4,
    const int* __restrict__ row_ptr, const int* __restrict__ col_src,
    float* __restrict__ hout,
    unsigned short* __restrict__ h_hi, unsigned short* __restrict__ h_lo,
    int n, int mode)
{
    __shared__ float lds[4][64 * 17];
    int node = (int)((blockIdx.x * (size_t)blockDim.x + threadIdx.x) >> 6);
    int lane = threadIdx.x & 63;
    int wl = threadIdx.x >> 6;
    if (node >= n) return;
    int h = lane >> 4, j = lane & 15;

    // q for this head, 16 chans = 2 uint4 (broadcast within 16-lane group)
    const uint4* q4 = (const uint4*)(qp + (size_t)node * 64 + h * 16);
    uint4 qa = q4[0], qb = q4[1];

    int e0 = row_ptr[node], e1 = row_ptr[node + 1];
    float acc[16];
    #pragma unroll
    for (int c = 0; c < 16; ++c) acc[c] = 0.f;
    float dsum = 0.f;

    for (int eb = e0; eb < e1; eb += 16) {
        int e = eb + j;
        int ec = (e < e1) ? e : (e1 - 1);
        int src = col_src[ec];
        const uint4* kvr = kv4 + (size_t)src * 16 + h * 2;
        uint4 ka = kvr[0], kb = kvr[1];
        uint4 va = kvr[8], vb = kvr[9];
        float s = 0.f;
        s = fdot2_acc(qa.x, ka.x, s);
        s = fdot2_acc(qa.y, ka.y, s);
        s = fdot2_acc(qa.z, ka.z, s);
        s = fdot2_acc(qa.w, ka.w, s);
        s = fdot2_acc(qb.x, kb.x, s);
        s = fdot2_acc(qb.y, kb.y, s);
        s = fdot2_acc(qb.z, kb.z, s);
        s = fdot2_acc(qb.w, kb.w, s);
        float p = (e < e1) ? __expf(s * 0.25f) : 0.f;
        dsum += p;
        unsigned uv[8] = {va.x, va.y, va.z, va.w, vb.x, vb.y, vb.z, vb.w};
        #pragma unroll
        for (int i = 0; i < 8; ++i) {
            __half2 hv = *(__half2*)&uv[i];
            acc[2 * i]     += p * __low2float(hv);
            acc[2 * i + 1] += p * __high2float(hv);
        }
    }

    // denominator: reduce over the 16 edge-slots of this head group
    dsum += __shfl_xor(dsum, 1, 64);
    dsum += __shfl_xor(dsum, 2, 64);
    dsum += __shfl_xor(dsum, 4, 64);
    dsum += __shfl_xor(dsum, 8, 64);
    float inv = 1.f / (dsum + 1e-16f);

    // numerator: transpose-reduce acc over edge-slots via LDS (stride 17, conflict-free)
    float* L = lds[wl];
    int wb = lane * 17;
    #pragma unroll
    for (int c = 0; c < 16; ++c) L[wb + c] = acc[c];
    __builtin_amdgcn_wave_barrier();
    float sum = 0.f;
    int rb = (h * 16) * 17 + j;       // this lane now owns channel c = j
    #pragma unroll
    for (int jj = 0; jj < 16; ++jj) sum += L[rb + jj * 17];

    float outv = sum * inv + sf[(size_t)node * 64 + lane];
    if (mode == 1) {
        outv = fmaxf(outv, 0.f);
        unsigned short hh = f2bf_rne(outv);
        unsigned short ll = f2bf_rne(outv - bf2f(hh));
        h_hi[(size_t)node * 64 + lane] = hh;
        h_lo[(size_t)node * 64 + lane] = ll;
    } else {
        hout[(size_t)node * 64 + lane] = outv;
    }
}

// ---------------- pooling + head ----------------
__global__ void graph_ranges_kernel(const int* __restrict__ bm, int* __restrict__ gstart,
                                    int n, int g) {
    int t = blockIdx.x * blockDim.x + threadIdx.x;
    if (t > g) return;
    if (t == g) { gstart[g] = n; return; }
    int lo = 0, hi = n;
    while (lo < hi) { int mid = (lo + hi) >> 1; if (bm[mid] < t) lo = mid + 1; else hi = mid; }
    gstart[t] = lo;
}

__global__ __launch_bounds__(256) void pool_kernel(
    const float* __restrict__ h, const int* __restrict__ gstart,
    float* __restrict__ pooled)
{
    int g = blockIdx.x;
    int c = threadIdx.x & 63, sub = threadIdx.x >> 6;
    int s = gstart[g], e = gstart[g + 1];
    float sum = 0.f;
    for (int i = s + sub; i < e; i += 4) sum += h[(size_t)i * 64 + c];
    __shared__ float tmp[256];
    tmp[threadIdx.x] = sum;
    __syncthreads();
    if (sub == 0) {
        sum = tmp[c] + tmp[c + 64] + tmp[c + 128] + tmp[c + 192];
        int cnt = e - s;
        pooled[g * 64 + c] = sum / fmaxf((float)cnt, 1.0f);
    }
}

__global__ void head_kernel(const float* __restrict__ pooled,
                            const float* __restrict__ Wl, const float* __restrict__ bl,
                            float* __restrict__ out)
{
    int g = blockIdx.x;
    int lane = threadIdx.x;
    __shared__ float pl[64];
    pl[lane] = pooled[g * 64 + lane];
    __syncthreads();
    float logit = -INFINITY;
    if (lane < NCLS) {
        float acc = bl[lane];
        for (int k = 0; k < 64; ++k) acc += pl[k] * Wl[k * NCLS + lane];
        logit = acc;
    }
    float mx = logit;
    mx = fmaxf(mx, __shfl_xor(mx, 1, 64));
    mx = fmaxf(mx, __shfl_xor(mx, 2, 64));
    mx = fmaxf(mx, __shfl_xor(mx, 4, 64));
    mx = fmaxf(mx, __shfl_xor(mx, 8, 64));
    float ex = (lane < NCLS) ? __expf(logit - mx) : 0.f;
    float sm = ex;
    sm += __shfl_xor(sm, 1, 64);
    sm += __shfl_xor(sm, 2, 64);
    sm += __shfl_xor(sm, 4, 64);
    sm += __shfl_xor(sm, 8, 64);
    if (lane < NCLS) out[g * NCLS + lane] = ex / sm;
}

// ---------------- launch ----------------
extern "C" void kernel_launch(void* const* d_in, const int* in_sizes, int n_in,
                              void* d_out, int out_size, void* d_ws, size_t ws_size,
                              hipStream_t stream) {
    const float* x  = (const float*)d_in[0];
    const int*   ei = (const int*)d_in[1];
    const int*   bm = (const int*)d_in[2];
    const float* W1[4] = {(const float*)d_in[3], (const float*)d_in[5], (const float*)d_in[7], (const float*)d_in[9]};
    const float* B1[4] = {(const float*)d_in[4], (const float*)d_in[6], (const float*)d_in[8], (const float*)d_in[10]};
    const float* W2[4] = {(const float*)d_in[11], (const float*)d_in[13], (const float*)d_in[15], (const float*)d_in[17]};
    const float* B2[4] = {(const float*)d_in[12], (const float*)d_in[14], (const float*)d_in[16], (const float*)d_in[18]};
    const float* W3[4] = {(const float*)d_in[19], (const float*)d_in[21], (const float*)d_in[23], (const float*)d_in[25]};
    const float* B3[4] = {(const float*)d_in[20], (const float*)d_in[22], (const float*)d_in[24], (const float*)d_in[26]};
    const float* Wl = (const float*)d_in[27];
    const float* bl = (const float*)d_in[28];
    float* outp = (float*)d_out;

    // workspace layout
    float* sf     = (float*)d_ws;                                 // NPAD*64 f32
    float* hf     = sf + (size_t)NPAD * 64;                       // NPAD*64 f32
    float* pooled = hf + (size_t)NPAD * 64;                       // NG*64
    unsigned short* qp16 = (unsigned short*)(pooled + NG * 64);   // NPAD*64 fp16
    unsigned short* kvpk = qp16 + (size_t)NPAD * 64;              // NPAD*128 fp16
    unsigned short* xs_hi = kvpk + (size_t)NPAD * 128;            // NPAD*128
    unsigned short* xs_lo = xs_hi + (size_t)NPAD * 128;
    unsigned short* hs_hi = xs_lo + (size_t)NPAD * 128;           // NPAD*64
    unsigned short* hs_lo = hs_hi + (size_t)NPAD * 64;
    unsigned short* wt_hi = hs_lo + (size_t)NPAD * 64;            // 3 * 4*64*128
    unsigned short* wt_lo = wt_hi + 3 * 4 * 64 * 128;
    int* row_ptr = (int*)(wt_lo + 3 * 4 * 64 * 128);              // N+1
    int* fillp   = row_ptr + (N_NODES + 1);
    int* counts  = fillp + N_NODES;
    int* excl    = counts + N_NODES;
    int* bsum    = excl + N_NODES;                                // 256
    int* boff    = bsum + 256;                                    // 256
    int* col_src = boff + 256;                                    // E
    int* gstart  = col_src + N_EDGES;                             // NG+1

    const int* srcp = ei;
    const int* dstp = ei + N_EDGES;

    // CSR build
    hipMemsetAsync(counts, 0, N_NODES * sizeof(int), stream);
    hist_kernel<<<(N_EDGES + 255) / 256, 256, 0, stream>>>(dstp, counts, N_EDGES);
    scanA_kernel<<<196, 256, 0, stream>>>(counts, excl, bsum, N_NODES);
    scanB_kernel<<<1, 256, 0, stream>>>(bsum, boff, 196);
    scanC_kernel<<<196, 256, 0, stream>>>(excl, boff, row_ptr, fillp, N_NODES);
    scatter_kernel<<<(N_EDGES + 255) / 256, 256, 0, stream>>>(srcp, dstp, fillp, col_src, N_EDGES);

    // conversions
    int n4x = N_NODES * F_IN / 4;
    split_kernel<<<(n4x + 255) / 256, 256, 0, stream>>>(x, xs_hi, xs_lo, n4x);
    wconv_kernel<<<(4 * 128 * 64 + 255) / 256, 256, 0, stream>>>(
        W1[0], W1[1], W1[2], W1[3], F_IN, wt_hi + 0 * 4 * 64 * 128, wt_lo + 0 * 4 * 64 * 128);
    wconv_kernel<<<(4 * 64 * 64 + 255) / 256, 256, 0, stream>>>(
        W2[0], W2[1], W2[2], W2[3], HC, wt_hi + 1 * 4 * 64 * 128, wt_lo + 1 * 4 * 64 * 128);
    wconv_kernel<<<(4 * 64 * 64 + 255) / 256, 256, 0, stream>>>(
        W3[0], W3[1], W3[2], W3[3], HC, wt_hi + 2 * 4 * 64 * 128, wt_lo + 2 * 4 * 64 * 128);

    int ggrid = 8 * XCHUNK * 4;
    int agrid = (N_NODES + 3) / 4;
    size_t smem1 = (size_t)4 * 64 * F_IN * 2;
    size_t smem2 = (size_t)4 * 64 * HC * 2;

    // layer 1
    mfma_gemm_kernel<<<ggrid, 256, smem1, stream>>>(xs_hi, xs_lo,
        wt_hi + 0 * 4 * 64 * 128, wt_lo + 0 * 4 * 64 * 128,
        B1[0], B1[1], B1[2], B1[3], qp16, sf, kvpk, N_NODES, F_IN);
    attn_kernel<<<agrid, 256, 0, stream>>>(qp16, sf, (const uint4*)kvpk, row_ptr, col_src,
                                           nullptr, hs_hi, hs_lo, N_NODES, 1);
    // layer 2
    mfma_gemm_kernel<<<ggrid, 256, smem2, stream>>>(hs_hi, hs_lo,
        wt_hi + 1 * 4 * 64 * 128, wt_lo + 1 * 4 * 64 * 128,
        B2[0], B2[1], B2[2], B2[3], qp16, sf, kvpk, N_NODES, HC);
    attn_kernel<<<agrid, 256, 0, stream>>>(qp16, sf, (const uint4*)kvpk, row_ptr, col_src,
                                           nullptr, hs_hi, hs_lo, N_NODES, 1);
    // layer 3
    mfma_gemm_kernel<<<ggrid, 256, smem2, stream>>>(hs_hi, hs_lo,
        wt_hi + 2 * 4 * 64 * 128, wt_lo + 2 * 4 * 64 * 128,
        B3[0], B3[1], B3[2], B3[3], qp16, sf, kvpk, N_NODES, HC);
    attn_kernel<<<agrid, 256, 0, stream>>>(qp16, sf, (const uint4*)kvpk, row_ptr, col_src,
                                           hf, nullptr, nullptr, N_NODES, 0);

    // pooling + head
    graph_ranges_kernel<<<1, 256, 0, stream>>>(bm, gstart, N_NODES, NG);
    pool_kernel<<<NG, 256, 0, stream>>>(hf, gstart, pooled);
    head_kernel<<<NG, 64, 0, stream>>>(pooled, Wl, bl, outp);
}

// Round 5
// 327.838 us; speedup vs baseline: 2.3277x; 1.0436x over previous
//
#include <hip/hip_runtime.h>
#include <hip/hip_fp16.h>
#include <math.h>

#define N_NODES 50000
#define NPAD    50048
#define N_EDGES 800000
#define F_IN    128
#define HC      64
#define NG      128
#define NCLS    10
#define NXT     782      // ceil(N_NODES/64) row tiles
#define XCHUNK  98       // ceil(NXT/8) tiles per XCD
#define DRANGE  6250     // N_NODES / 8 dst-range per XCD group

typedef __attribute__((ext_vector_type(8))) short bfrag;   // 8 bf16 (4 VGPR)
typedef __attribute__((ext_vector_type(4))) float f32x4;
typedef _Float16 half2v __attribute__((ext_vector_type(2)));

__device__ __forceinline__ unsigned short f2bf_rne(float f) {
    unsigned u = __float_as_uint(f);
    unsigned r = u + 0x7FFF + ((u >> 16) & 1);
    return (unsigned short)(r >> 16);
}
__device__ __forceinline__ float bf2f(unsigned short h) {
    return __uint_as_float(((unsigned)h) << 16);
}

__device__ __forceinline__ float fdot2_acc(unsigned a, unsigned b, float c) {
#if __has_builtin(__builtin_amdgcn_fdot2)
    half2v ha, hb;
    __builtin_memcpy(&ha, &a, 4);
    __builtin_memcpy(&hb, &b, 4);
    return __builtin_amdgcn_fdot2(ha, hb, c, false);
#else
    __half2 ha = *(__half2*)&a, hb = *(__half2*)&b;
    return c + __low2float(ha) * __low2float(hb) + __high2float(ha) * __high2float(hb);
#endif
}

// ---------------- CSR build, dst-range partitioned (XCD-local atomics/writes) ----------------
// blocks with (blockIdx.x % 8 == g) own dst range [g*DRANGE, (g+1)*DRANGE);
// round-robin dispatch pins group g's atomics + col_src writes to one XCD's L2,
// so cache lines fill completely before writeback (52 MB -> ~4 MB HBM writes).
__global__ __launch_bounds__(256) void hist_part_kernel(const int* __restrict__ dst,
                                                        int* __restrict__ counts, int e) {
    int grp = blockIdx.x & 7;
    int nb = gridDim.x >> 3;
    int slot = blockIdx.x >> 3;
    int lo = grp * DRANGE, hi = lo + DRANGE;
    for (int t = slot * 256 + threadIdx.x; t < e; t += nb * 256) {
        int d = dst[t];
        if (d >= lo && d < hi) atomicAdd(&counts[d], 1);
    }
}

__global__ __launch_bounds__(256) void scatter_part_kernel(const int* __restrict__ src,
                                                           const int* __restrict__ dst,
                                                           int* __restrict__ fillp,
                                                           int* __restrict__ col_src, int e) {
    int grp = blockIdx.x & 7;
    int nb = gridDim.x >> 3;
    int slot = blockIdx.x >> 3;
    int lo = grp * DRANGE, hi = lo + DRANGE;
    for (int t = slot * 256 + threadIdx.x; t < e; t += nb * 256) {
        int d = dst[t];
        if (d >= lo && d < hi) {
            int pos = atomicAdd(&fillp[d], 1);
            col_src[pos] = src[t];
        }
    }
}

__global__ __launch_bounds__(256) void scanA_kernel(const int* __restrict__ counts,
                                                    int* __restrict__ excl,
                                                    int* __restrict__ bsum, int n) {
    int tid = threadIdx.x, bid = blockIdx.x;
    int i = bid * 256 + tid;
    int v = (i < n) ? counts[i] : 0;
    int lane = tid & 63, wid = tid >> 6;
    int sc = v;
    #pragma unroll
    for (int off = 1; off < 64; off <<= 1) {
        int t = __shfl_up(sc, off, 64);
        if (lane >= off) sc += t;
    }
    __shared__ int ws[4];
    if (lane == 63) ws[wid] = sc;
    __syncthreads();
    int add = 0;
    #pragma unroll
    for (int k = 0; k < 4; ++k) if (k < wid) add += ws[k];
    int incl = sc + add;
    if (i < n) excl[i] = incl - v;
    if (tid == 255) bsum[bid] = incl;
}

__global__ __launch_bounds__(256) void scanB_kernel(const int* __restrict__ bsum,
                                                    int* __restrict__ boff, int nb) {
    int tid = threadIdx.x;
    int v = (tid < nb) ? bsum[tid] : 0;
    int lane = tid & 63, wid = tid >> 6;
    int sc = v;
    #pragma unroll
    for (int off = 1; off < 64; off <<= 1) {
        int t = __shfl_up(sc, off, 64);
        if (lane >= off) sc += t;
    }
    __shared__ int ws[4];
    if (lane == 63) ws[wid] = sc;
    __syncthreads();
    int add = 0;
    #pragma unroll
    for (int k = 0; k < 4; ++k) if (k < wid) add += ws[k];
    if (tid < nb) boff[tid] = sc + add - v;
}

__global__ __launch_bounds__(256) void scanC_kernel(const int* __restrict__ excl,
                                                    const int* __restrict__ boff,
                                                    int* __restrict__ row_ptr,
                                                    int* __restrict__ fillp, int n) {
    int i = blockIdx.x * 256 + threadIdx.x;
    if (i < n) {
        int r = excl[i] + boff[i >> 8];
        row_ptr[i] = r;
        fillp[i] = r;
    }
    if (i == n) row_ptr[n] = N_EDGES;
}

// ---------------- fp32 -> bf16 hi/lo split (x input) ----------------
__global__ void split_kernel(const float* __restrict__ in, unsigned short* __restrict__ hi,
                             unsigned short* __restrict__ lo, int n4) {
    int t = blockIdx.x * blockDim.x + threadIdx.x;
    if (t >= n4) return;
    float4 f = ((const float4*)in)[t];
    unsigned short h[4], l[4];
    float ff[4] = {f.x, f.y, f.z, f.w};
    #pragma unroll
    for (int i = 0; i < 4; ++i) {
        h[i] = f2bf_rne(ff[i]);
        l[i] = f2bf_rne(ff[i] - bf2f(h[i]));
    }
    ((ushort4*)hi)[t] = make_ushort4(h[0], h[1], h[2], h[3]);
    ((ushort4*)lo)[t] = make_ushort4(l[0], l[1], l[2], l[3]);
}

// ---------------- W [K][64] fp32 -> transposed bf16 hi/lo [mat][64][K] ----------------
__global__ void wconv_kernel(const float* __restrict__ W0, const float* __restrict__ W1,
                             const float* __restrict__ W2, const float* __restrict__ W3,
                             int K, unsigned short* __restrict__ wt_hi,
                             unsigned short* __restrict__ wt_lo) {
    int t = blockIdx.x * blockDim.x + threadIdx.x;
    int per = K * 64;
    if (t >= 4 * per) return;
    int mat = t / per, r = t - mat * per;
    int k = r >> 6, c = r & 63;
    const float* W = (mat == 0) ? W0 : (mat == 1) ? W1 : (mat == 2) ? W2 : W3;
    float f = W[k * 64 + c];
    unsigned short h = f2bf_rne(f);
    unsigned short l = f2bf_rne(f - bf2f(h));
    int idx = mat * per + c * K + k;
    wt_hi[idx] = h;
    wt_lo[idx] = l;
}

// ---------------- split-bf16 MFMA GEMM ----------------
// y=0 -> qp16 fp16, y=3 -> sf fp32, y=1 -> kvpk k-block fp16, y=2 -> kvpk v-block fp16
__global__ __launch_bounds__(256) void mfma_gemm_kernel(
    const unsigned short* __restrict__ A_hi, const unsigned short* __restrict__ A_lo,
    const unsigned short* __restrict__ Wt_hi, const unsigned short* __restrict__ Wt_lo,
    const float* __restrict__ b0, const float* __restrict__ b1,
    const float* __restrict__ b2, const float* __restrict__ b3,
    unsigned short* __restrict__ qp16, float* __restrict__ sf,
    unsigned short* __restrict__ kvpk,
    int M, int K)
{
    int bid = blockIdx.x;
    int xcd = bid & 7;
    int slot = bid >> 3;
    int xt = xcd * XCHUNK + (slot >> 2);
    int y = slot & 3;
    if (xt >= NXT) return;
    int row0 = xt * 64;

    extern __shared__ char smem[];
    const int tileU = 64 * K;
    unsigned short* sA_hi = (unsigned short*)smem;
    unsigned short* sA_lo = sA_hi + tileU;
    unsigned short* sB_hi = sA_lo + tileU;
    unsigned short* sB_lo = sB_hi + tileU;

    int tid = threadIdx.x;
    int cpr = K >> 3;
    int total = 64 * cpr;
    const bfrag* gAh = (const bfrag*)(A_hi + (size_t)row0 * K);
    const bfrag* gAl = (const bfrag*)(A_lo + (size_t)row0 * K);
    const bfrag* gBh = (const bfrag*)(Wt_hi + (size_t)y * tileU);
    const bfrag* gBl = (const bfrag*)(Wt_lo + (size_t)y * tileU);
    for (int t = tid; t < total; t += 256) {
        int row = t / cpr, cs = t - row * cpr;
        int dstB = row * (K * 2) + ((cs * 16) ^ ((row & 7) << 4));
        *(bfrag*)((char*)sA_hi + dstB) = gAh[t];
        *(bfrag*)((char*)sA_lo + dstB) = gAl[t];
        *(bfrag*)((char*)sB_hi + dstB) = gBh[t];
        *(bfrag*)((char*)sB_lo + dstB) = gBl[t];
    }
    __syncthreads();

    int w = tid >> 6, lane = tid & 63, lr = lane & 15, kq = lane >> 4;
    f32x4 acc[4];
    #pragma unroll
    for (int f = 0; f < 4; ++f) acc[f] = (f32x4){0.f, 0.f, 0.f, 0.f};

    int arow = w * 16 + lr;
    int abase = arow * (K * 2);
    int aswz = (arow & 7) << 4;
    for (int ks = 0; ks < K; ks += 32) {
        int kb = ks * 2 + kq * 16;
        bfrag ah = *(const bfrag*)((const char*)sA_hi + abase + (kb ^ aswz));
        bfrag al = *(const bfrag*)((const char*)sA_lo + abase + (kb ^ aswz));
        #pragma unroll
        for (int f = 0; f < 4; ++f) {
            int brow = f * 16 + lr;
            int boff = brow * (K * 2) + (kb ^ ((brow & 7) << 4));
            bfrag bh = *(const bfrag*)((const char*)sB_hi + boff);
            bfrag bl = *(const bfrag*)((const char*)sB_lo + boff);
            acc[f] = __builtin_amdgcn_mfma_f32_16x16x32_bf16(ah, bh, acc[f], 0, 0, 0);
            acc[f] = __builtin_amdgcn_mfma_f32_16x16x32_bf16(ah, bl, acc[f], 0, 0, 0);
            acc[f] = __builtin_amdgcn_mfma_f32_16x16x32_bf16(al, bh, acc[f], 0, 0, 0);
        }
    }

    const float* bias = (y == 0) ? b0 : (y == 1) ? b1 : (y == 2) ? b2 : b3;
    if (y == 3) {
        #pragma unroll
        for (int f = 0; f < 4; ++f) {
            float bv = bias[f * 16 + lr];
            #pragma unroll
            for (int r = 0; r < 4; ++r) {
                int gr = row0 + w * 16 + kq * 4 + r;
                if (gr < M) sf[(size_t)gr * 64 + f * 16 + lr] = acc[f][r] + bv;
            }
        }
    } else if (y == 0) {
        #pragma unroll
        for (int f = 0; f < 4; ++f) {
            float bv = bias[f * 16 + lr];
            #pragma unroll
            for (int r = 0; r < 4; ++r) {
                int gr = row0 + w * 16 + kq * 4 + r;
                if (gr < M)
                    qp16[(size_t)gr * 64 + f * 16 + lr] =
                        __half_as_ushort(__float2half_rn(acc[f][r] + bv));
            }
        }
    } else {
        int off = (y == 1) ? 0 : 64;   // k-block then v-block
        #pragma unroll
        for (int f = 0; f < 4; ++f) {
            float bv = bias[f * 16 + lr];
            #pragma unroll
            for (int r = 0; r < 4; ++r) {
                int gr = row0 + w * 16 + kq * 4 + r;
                if (gr < M)
                    kvpk[(size_t)gr * 128 + off + f * 16 + lr] =
                        __half_as_ushort(__float2half_rn(acc[f][r] + bv));
            }
        }
    }
}

// ---------------- attention: wave per dst node, lane = (head, edge-slot) ----------------
__global__ __launch_bounds__(256) void attn_kernel(
    const unsigned short* __restrict__ qp, const float* __restrict__ sf,
    const uint4* __restrict__ kv4,
    const int* __restrict__ row_ptr, const int* __restrict__ col_src,
    float* __restrict__ hout,
    unsigned short* __restrict__ h_hi, unsigned short* __restrict__ h_lo,
    int n, int mode)
{
    __shared__ float lds[4][64 * 17];
    int node = (int)((blockIdx.x * (size_t)blockDim.x + threadIdx.x) >> 6);
    int lane = threadIdx.x & 63;
    int wl = threadIdx.x >> 6;
    if (node >= n) return;
    int h = lane >> 4, j = lane & 15;

    const uint4* q4 = (const uint4*)(qp + (size_t)node * 64 + h * 16);
    uint4 qa = q4[0], qb = q4[1];

    int e0 = row_ptr[node], e1 = row_ptr[node + 1];
    float acc[16];
    #pragma unroll
    for (int c = 0; c < 16; ++c) acc[c] = 0.f;
    float dsum = 0.f;

    for (int eb = e0; eb < e1; eb += 16) {
        int e = eb + j;
        int ec = (e < e1) ? e : (e1 - 1);
        int src = col_src[ec];
        const uint4* kvr = kv4 + (size_t)src * 16 + h * 2;
        uint4 ka = kvr[0], kb = kvr[1];
        uint4 va = kvr[8], vb = kvr[9];
        float s = 0.f;
        s = fdot2_acc(qa.x, ka.x, s);
        s = fdot2_acc(qa.y, ka.y, s);
        s = fdot2_acc(qa.z, ka.z, s);
        s = fdot2_acc(qa.w, ka.w, s);
        s = fdot2_acc(qb.x, kb.x, s);
        s = fdot2_acc(qb.y, kb.y, s);
        s = fdot2_acc(qb.z, kb.z, s);
        s = fdot2_acc(qb.w, kb.w, s);
        float p = (e < e1) ? __expf(s * 0.25f) : 0.f;
        dsum += p;
        unsigned uv[8] = {va.x, va.y, va.z, va.w, vb.x, vb.y, vb.z, vb.w};
        #pragma unroll
        for (int i = 0; i < 8; ++i) {
            __half2 hv = *(__half2*)&uv[i];
            acc[2 * i]     += p * __low2float(hv);
            acc[2 * i + 1] += p * __high2float(hv);
        }
    }

    dsum += __shfl_xor(dsum, 1, 64);
    dsum += __shfl_xor(dsum, 2, 64);
    dsum += __shfl_xor(dsum, 4, 64);
    dsum += __shfl_xor(dsum, 8, 64);
    float inv = 1.f / (dsum + 1e-16f);

    float* L = lds[wl];
    int wb = lane * 17;
    #pragma unroll
    for (int c = 0; c < 16; ++c) L[wb + c] = acc[c];
    __builtin_amdgcn_wave_barrier();
    float sum = 0.f;
    int rb = (h * 16) * 17 + j;
    #pragma unroll
    for (int jj = 0; jj < 16; ++jj) sum += L[rb + jj * 17];

    float outv = sum * inv + sf[(size_t)node * 64 + lane];
    if (mode == 1) {
        outv = fmaxf(outv, 0.f);
        unsigned short hh = f2bf_rne(outv);
        unsigned short ll = f2bf_rne(outv - bf2f(hh));
        h_hi[(size_t)node * 64 + lane] = hh;
        h_lo[(size_t)node * 64 + lane] = ll;
    } else {
        hout[(size_t)node * 64 + lane] = outv;
    }
}

// ---------------- pooling + head ----------------
__global__ void graph_ranges_kernel(const int* __restrict__ bm, int* __restrict__ gstart,
                                    int n, int g) {
    int t = blockIdx.x * blockDim.x + threadIdx.x;
    if (t > g) return;
    if (t == g) { gstart[g] = n; return; }
    int lo = 0, hi = n;
    while (lo < hi) { int mid = (lo + hi) >> 1; if (bm[mid] < t) lo = mid + 1; else hi = mid; }
    gstart[t] = lo;
}

__global__ __launch_bounds__(256) void pool_kernel(
    const float* __restrict__ h, const int* __restrict__ gstart,
    float* __restrict__ pooled)
{
    int g = blockIdx.x;
    int c = threadIdx.x & 63, sub = threadIdx.x >> 6;
    int s = gstart[g], e = gstart[g + 1];
    float sum = 0.f;
    for (int i = s + sub; i < e; i += 4) sum += h[(size_t)i * 64 + c];
    __shared__ float tmp[256];
    tmp[threadIdx.x] = sum;
    __syncthreads();
    if (sub == 0) {
        sum = tmp[c] + tmp[c + 64] + tmp[c + 128] + tmp[c + 192];
        int cnt = e - s;
        pooled[g * 64 + c] = sum / fmaxf((float)cnt, 1.0f);
    }
}

__global__ void head_kernel(const float* __restrict__ pooled,
                            const float* __restrict__ Wl, const float* __restrict__ bl,
                            float* __restrict__ out)
{
    int g = blockIdx.x;
    int lane = threadIdx.x;
    __shared__ float pl[64];
    pl[lane] = pooled[g * 64 + lane];
    __syncthreads();
    float logit = -INFINITY;
    if (lane < NCLS) {
        float acc = bl[lane];
        for (int k = 0; k < 64; ++k) acc += pl[k] * Wl[k * NCLS + lane];
        logit = acc;
    }
    float mx = logit;
    mx = fmaxf(mx, __shfl_xor(mx, 1, 64));
    mx = fmaxf(mx, __shfl_xor(mx, 2, 64));
    mx = fmaxf(mx, __shfl_xor(mx, 4, 64));
    mx = fmaxf(mx, __shfl_xor(mx, 8, 64));
    float ex = (lane < NCLS) ? __expf(logit - mx) : 0.f;
    float sm = ex;
    sm += __shfl_xor(sm, 1, 64);
    sm += __shfl_xor(sm, 2, 64);
    sm += __shfl_xor(sm, 4, 64);
    sm += __shfl_xor(sm, 8, 64);
    if (lane < NCLS) out[g * NCLS + lane] = ex / sm;
}

// ---------------- launch ----------------
extern "C" void kernel_launch(void* const* d_in, const int* in_sizes, int n_in,
                              void* d_out, int out_size, void* d_ws, size_t ws_size,
                              hipStream_t stream) {
    const float* x  = (const float*)d_in[0];
    const int*   ei = (const int*)d_in[1];
    const int*   bm = (const int*)d_in[2];
    const float* W1[4] = {(const float*)d_in[3], (const float*)d_in[5], (const float*)d_in[7], (const float*)d_in[9]};
    const float* B1[4] = {(const float*)d_in[4], (const float*)d_in[6], (const float*)d_in[8], (const float*)d_in[10]};
    const float* W2[4] = {(const float*)d_in[11], (const float*)d_in[13], (const float*)d_in[15], (const float*)d_in[17]};
    const float* B2[4] = {(const float*)d_in[12], (const float*)d_in[14], (const float*)d_in[16], (const float*)d_in[18]};
    const float* W3[4] = {(const float*)d_in[19], (const float*)d_in[21], (const float*)d_in[23], (const float*)d_in[25]};
    const float* B3[4] = {(const float*)d_in[20], (const float*)d_in[22], (const float*)d_in[24], (const float*)d_in[26]};
    const float* Wl = (const float*)d_in[27];
    const float* bl = (const float*)d_in[28];
    float* outp = (float*)d_out;

    // workspace layout
    float* sf     = (float*)d_ws;                                 // NPAD*64 f32
    float* hf     = sf + (size_t)NPAD * 64;                       // NPAD*64 f32
    float* pooled = hf + (size_t)NPAD * 64;                       // NG*64
    unsigned short* qp16 = (unsigned short*)(pooled + NG * 64);   // NPAD*64 fp16
    unsigned short* kvpk = qp16 + (size_t)NPAD * 64;              // NPAD*128 fp16
    unsigned short* xs_hi = kvpk + (size_t)NPAD * 128;            // NPAD*128
    unsigned short* xs_lo = xs_hi + (size_t)NPAD * 128;
    unsigned short* hs_hi = xs_lo + (size_t)NPAD * 128;           // NPAD*64
    unsigned short* hs_lo = hs_hi + (size_t)NPAD * 64;
    unsigned short* wt_hi = hs_lo + (size_t)NPAD * 64;            // 3 * 4*64*128
    unsigned short* wt_lo = wt_hi + 3 * 4 * 64 * 128;
    int* row_ptr = (int*)(wt_lo + 3 * 4 * 64 * 128);              // N+1
    int* fillp   = row_ptr + (N_NODES + 1);
    int* counts  = fillp + N_NODES;
    int* excl    = counts + N_NODES;
    int* bsum    = excl + N_NODES;                                // 256
    int* boff    = bsum + 256;                                    // 256
    int* col_src = boff + 256;                                    // E
    int* gstart  = col_src + N_EDGES;                             // NG+1

    const int* srcp = ei;
    const int* dstp = ei + N_EDGES;

    // CSR build (dst-range partitioned: XCD-local atomics + writes)
    hipMemsetAsync(counts, 0, N_NODES * sizeof(int), stream);
    hist_part_kernel<<<1024, 256, 0, stream>>>(dstp, counts, N_EDGES);
    scanA_kernel<<<196, 256, 0, stream>>>(counts, excl, bsum, N_NODES);
    scanB_kernel<<<1, 256, 0, stream>>>(bsum, boff, 196);
    scanC_kernel<<<196, 256, 0, stream>>>(excl, boff, row_ptr, fillp, N_NODES);
    scatter_part_kernel<<<1024, 256, 0, stream>>>(srcp, dstp, fillp, col_src, N_EDGES);

    // conversions
    int n4x = N_NODES * F_IN / 4;
    split_kernel<<<(n4x + 255) / 256, 256, 0, stream>>>(x, xs_hi, xs_lo, n4x);
    wconv_kernel<<<(4 * 128 * 64 + 255) / 256, 256, 0, stream>>>(
        W1[0], W1[1], W1[2], W1[3], F_IN, wt_hi + 0 * 4 * 64 * 128, wt_lo + 0 * 4 * 64 * 128);
    wconv_kernel<<<(4 * 64 * 64 + 255) / 256, 256, 0, stream>>>(
        W2[0], W2[1], W2[2], W2[3], HC, wt_hi + 1 * 4 * 64 * 128, wt_lo + 1 * 4 * 64 * 128);
    wconv_kernel<<<(4 * 64 * 64 + 255) / 256, 256, 0, stream>>>(
        W3[0], W3[1], W3[2], W3[3], HC, wt_hi + 2 * 4 * 64 * 128, wt_lo + 2 * 4 * 64 * 128);

    int ggrid = 8 * XCHUNK * 4;
    int agrid = (N_NODES + 3) / 4;
    size_t smem1 = (size_t)4 * 64 * F_IN * 2;
    size_t smem2 = (size_t)4 * 64 * HC * 2;

    // layer 1
    mfma_gemm_kernel<<<ggrid, 256, smem1, stream>>>(xs_hi, xs_lo,
        wt_hi + 0 * 4 * 64 * 128, wt_lo + 0 * 4 * 64 * 128,
        B1[0], B1[1], B1[2], B1[3], qp16, sf, kvpk, N_NODES, F_IN);
    attn_kernel<<<agrid, 256, 0, stream>>>(qp16, sf, (const uint4*)kvpk, row_ptr, col_src,
                                           nullptr, hs_hi, hs_lo, N_NODES, 1);
    // layer 2
    mfma_gemm_kernel<<<ggrid, 256, smem2, stream>>>(hs_hi, hs_lo,
        wt_hi + 1 * 4 * 64 * 128, wt_lo + 1 * 4 * 64 * 128,
        B2[0], B2[1], B2[2], B2[3], qp16, sf, kvpk, N_NODES, HC);
    attn_kernel<<<agrid, 256, 0, stream>>>(qp16, sf, (const uint4*)kvpk, row_ptr, col_src,
                                           nullptr, hs_hi, hs_lo, N_NODES, 1);
    // layer 3
    mfma_gemm_kernel<<<ggrid, 256, smem2, stream>>>(hs_hi, hs_lo,
        wt_hi + 2 * 4 * 64 * 128, wt_lo + 2 * 4 * 64 * 128,
        B3[0], B3[1], B3[2], B3[3], qp16, sf, kvpk, N_NODES, HC);
    attn_kernel<<<agrid, 256, 0, stream>>>(qp16, sf, (const uint4*)kvpk, row_ptr, col_src,
                                           hf, nullptr, nullptr, N_NODES, 0);

    // pooling + head
    graph_ranges_kernel<<<1, 256, 0, stream>>>(bm, gstart, N_NODES, NG);
    pool_kernel<<<NG, 256, 0, stream>>>(hf, gstart, pooled);
    head_kernel<<<NG, 64, 0, stream>>>(pooled, Wl, bl, outp);
}